// Round 1
// baseline (3085.243 us; speedup 1.0000x reference)
//
#include <hip/hip_runtime.h>
#include <cstdint>
#include <cstddef>

// Problem constants
#define T_TOKN 16
#define NUNITS 4096
#define LPATH  32
#define NPATHS 1024
#define BNUM   8

// ws float offsets
enum : size_t {
  OFF_WCTF   = 0,                       // 256x512 reordered [Wi|Wh]^T, token fwd
  OFF_WCTB   = OFF_WCTF + 131072,
  OFF_WCPF   = OFF_WCTB + 131072,
  OFF_WCPB   = OFF_WCPF + 131072,
  OFF_BC     = OFF_WCPB + 131072,       // 4 x 512 reordered biases (tf, tb, pf, pb)
  OFF_LINWT  = OFF_BC + 2048,           // lin_W^T  [k][e] 256x128
  OFF_ULWT   = OFF_LINWT + 32768,       // ul_W^T
  OFF_OUTF   = OFF_ULWT + 32768,        // token fwd h: 16x4096x128
  OFF_OUTB   = OFF_OUTF + 8388608,      // token bwd h (time-realigned)
  OFF_OUTLIN = OFF_OUTB + 8388608,      // 16x4096x128
  OFF_SCORES = OFF_OUTLIN + 8388608,    // 16x4096
  OFF_TOKFEAT= OFF_SCORES + 65536,      // 4096x128
  OFF_POUTF  = OFF_TOKFEAT + 524288,    // 32x1024x128
  OFF_POUTB  = OFF_POUTF + 4194304,
  OFF_INT    = OFF_POUTB + 4194304,     // int area: tok_len 4096 | fe 1024 | p_len 1024 | off_p 1024 | un_p 1024
  WS_FLOATS  = OFF_INT + 8192
};

static __device__ __forceinline__ float sigf(float x) { return 1.f / (1.f + expf(-x)); }

// ---------------------------------------------------------------------------
// Weight reorder: WcT[k][r], r = 4*j + q  <->  gate g = q*128 + j,
// k<128 -> Wi[g][k], k>=128 -> Wh[g][k-128].  Also bc[r] = b[g].
// linWT/ulWT: [k][e] transposed copies.
// ---------------------------------------------------------------------------
__global__ void prep_kernel(
    const float* __restrict__ tWif, const float* __restrict__ tWhf, const float* __restrict__ tbf,
    const float* __restrict__ tWib, const float* __restrict__ tWhb, const float* __restrict__ tbb,
    const float* __restrict__ pWif, const float* __restrict__ pWhf, const float* __restrict__ pbf,
    const float* __restrict__ pWib, const float* __restrict__ pWhb, const float* __restrict__ pbb,
    const float* __restrict__ linW, const float* __restrict__ ulW,
    float* __restrict__ ws)
{
  int idx = blockIdx.x * 256 + threadIdx.x;
  if (idx < 524288) {
    int s = idx >> 17; int rem = idx & 131071;
    int k = rem >> 9;  int r = rem & 511;
    int jj = r >> 2, q = r & 3;
    int g = q * 128 + jj;
    const float* Wi; const float* Wh;
    switch (s) {
      case 0: Wi = tWif; Wh = tWhf; break;
      case 1: Wi = tWib; Wh = tWhb; break;
      case 2: Wi = pWif; Wh = pWhf; break;
      default: Wi = pWib; Wh = pWhb; break;
    }
    ws[OFF_WCTF + idx] = (k < 128) ? Wi[g * 128 + k] : Wh[g * 128 + (k - 128)];
  } else if (idx < 524288 + 2048) {
    int i = idx - 524288;
    int s = i >> 9; int r = i & 511;
    int g = (r & 3) * 128 + (r >> 2);
    const float* b = (s == 0) ? tbf : (s == 1) ? tbb : (s == 2) ? pbf : pbb;
    ws[OFF_BC + i] = b[g];
  } else if (idx < 524288 + 2048 + 65536) {
    int i = idx - (524288 + 2048);
    int s = i >> 15; int rem = i & 32767;
    int k = rem >> 7, e = rem & 127;
    const float* W = s ? ulW : linW;
    ws[OFF_LINWT + i] = W[e * 256 + k];
  }
}

// ---------------------------------------------------------------------------
// Lengths / path metadata
// ---------------------------------------------------------------------------
__global__ void len_kernel(const int* __restrict__ units, const int* __restrict__ paths,
                           const int* __restrict__ upd, const int* __restrict__ ppd,
                           int* __restrict__ ip)
{
  int idx = blockIdx.x * 256 + threadIdx.x;
  int* tok_len = ip;
  int* fe_a    = ip + 4096;
  int* p_len   = ip + 5120;
  int* off_p   = ip + 6144;
  int* un_p    = ip + 7168;
  if (idx < 4096) {
    int len = T_TOKN;
    for (int t = 0; t < T_TOKN; ++t)
      if (units[t * NUNITS + idx] == 0) { len = t; break; }
    tok_len[idx] = len;
  } else if (idx < 5120) {
    int p = idx - 4096;
    int cum = 0; int d = BNUM - 1;
    for (int dd = 0; dd < BNUM; ++dd) {
      int c2 = cum + ppd[dd];
      if (p < c2) { d = dd; break; }
      cum = c2;
    }
    int off = 0;
    for (int dd = 0; dd < d; ++dd) off += upd[dd];
    int un = upd[d];
    off_p[p] = off; un_p[p] = un;
    int f = LPATH;
    for (int t = 0; t < LPATH; ++t)
      if (paths[t * NPATHS + p] == -1) { f = t; break; }
    fe_a[p] = f;
    int pl = LPATH;
    for (int t = 0; t < LPATH; ++t) {
      int v = paths[t * NPATHS + p];
      if ((t >= f) || (v < 0) || (v > un)) { pl = t; break; }
    }
    p_len[p] = pl;
  }
}

// ---------------------------------------------------------------------------
// Fused BiLSTM: each block owns M sequences for one direction, loops all T
// steps internally.  Gates = [x;h] @ WcT (K=256) with W streamed through LDS
// (32KB chunks, register-prefetched).  Thread = (j, 4 units): computes the 4
// gates of hidden j for 4 units; c stays in registers, h in LDS.
// MODE 0: token (gather emb[units]); MODE 1: path (gather tok_feat w/ keep).
// ---------------------------------------------------------------------------
template <int MODE>
__global__ __launch_bounds__(MODE ? 256 : 512) void lstm_kernel(
    const float* __restrict__ Wcf, const float* __restrict__ Wcb,
    const float* __restrict__ bcf, const float* __restrict__ bcb,
    const float* __restrict__ src,       // emb or tok_feat
    const int* __restrict__ idxsrc,      // units or paths
    const int* __restrict__ lens,        // tok_len or p_len
    const int* __restrict__ fe_a, const int* __restrict__ off_p, const int* __restrict__ un_p,
    float* __restrict__ outF, float* __restrict__ outB)
{
  constexpr int NN   = MODE ? NPATHS : NUNITS;
  constexpr int TT   = MODE ? LPATH : T_TOKN;
  constexpr int M    = MODE ? 8 : 16;
  constexpr int NTHR = MODE ? 256 : 512;
  constexpr int NPF  = (16 * 512) / (NTHR * 4);   // float4 prefetch regs per thread

  __shared__ float XH[256 * M];   // [k][u]; k<128 = x, k>=128 = h_prev
  __shared__ float WS[16 * 512];  // one K-chunk of WcT, [kk][r]

  int tid = threadIdx.x;
  int dir = blockIdx.y;
  int nb  = blockIdx.x * M;
  const float* Wc  = dir ? Wcb : Wcf;
  const float* bcp = dir ? bcb : bcf;
  int j  = tid & 127;
  int u4 = (tid >> 7) << 2;

  float bias[4];
#pragma unroll
  for (int q = 0; q < 4; ++q) bias[q] = bcp[4 * j + q];
  float cst[4] = {0.f, 0.f, 0.f, 0.f};

  for (int i = tid; i < 128 * M; i += NTHR) XH[128 * M + i] = 0.f;  // h0 = 0

  float4 pf[NPF];
#pragma unroll
  for (int n = 0; n < NPF; ++n)
    pf[n] = *(const float4*)&Wc[tid * 4 + n * NTHR * 4];

  for (int t = 0; t < TT; ++t) {
    __syncthreads();
    // ---- gather x for this step ----
    {
      int u  = tid & (M - 1);
      int k0 = (tid / M) * 4;
      int n  = nb + u;
      float4 x;
      if (MODE == 0) {
        int len = lens[n];
        int tau = dir ? min(max(len - 1 - t, 0), TT - 1) : t;
        int tok = idxsrc[tau * NN + n];
        x = *(const float4*)&src[(size_t)tok * 128 + k0];
      } else {
        int pl  = lens[n];
        int tau = dir ? min(max(pl - 1 - t, 0), TT - 1) : t;
        int v   = idxsrc[tau * NN + n];
        bool keep = (tau < fe_a[n]) && (v >= 0) && (v < un_p[n]);
        if (keep) {
          int gi = min(max(v, 0) + off_p[n], NUNITS - 1);
          x = *(const float4*)&src[(size_t)gi * 128 + k0];
        } else {
          x = make_float4(0.f, 0.f, 0.f, 0.f);
        }
      }
      XH[(k0 + 0) * M + u] = x.x;
      XH[(k0 + 1) * M + u] = x.y;
      XH[(k0 + 2) * M + u] = x.z;
      XH[(k0 + 3) * M + u] = x.w;
    }
    __syncthreads();

    // ---- gate GEMM, K = 256 ----
    float acc[4][4];
#pragma unroll
    for (int q = 0; q < 4; ++q) {
      acc[q][0] = bias[q]; acc[q][1] = bias[q]; acc[q][2] = bias[q]; acc[q][3] = bias[q];
    }
    for (int kc = 0; kc < 256; kc += 16) {
      __syncthreads();   // previous chunk's compute done
#pragma unroll
      for (int n = 0; n < NPF; ++n)
        *(float4*)&WS[tid * 4 + n * NTHR * 4] = pf[n];
      __syncthreads();   // WS ready
      if (kc + 16 < 256) {
#pragma unroll
        for (int n = 0; n < NPF; ++n)
          pf[n] = *(const float4*)&Wc[(kc + 16) * 512 + tid * 4 + n * NTHR * 4];
      } else if (t + 1 < TT) {
#pragma unroll
        for (int n = 0; n < NPF; ++n)
          pf[n] = *(const float4*)&Wc[tid * 4 + n * NTHR * 4];
      }
#pragma unroll
      for (int kk = 0; kk < 16; ++kk) {
        float4 w  = *(float4*)&WS[kk * 512 + 4 * j];
        float4 xh = *(float4*)&XH[(kc + kk) * M + u4];
        acc[0][0] += w.x * xh.x; acc[0][1] += w.x * xh.y; acc[0][2] += w.x * xh.z; acc[0][3] += w.x * xh.w;
        acc[1][0] += w.y * xh.x; acc[1][1] += w.y * xh.y; acc[1][2] += w.y * xh.z; acc[1][3] += w.y * xh.w;
        acc[2][0] += w.z * xh.x; acc[2][1] += w.z * xh.y; acc[2][2] += w.z * xh.z; acc[2][3] += w.z * xh.w;
        acc[3][0] += w.w * xh.x; acc[3][1] += w.w * xh.y; acc[3][2] += w.w * xh.z; acc[3][3] += w.w * xh.w;
      }
    }
    __syncthreads();   // all XH reads done before h overwrite

    // ---- pointwise LSTM update ----
    float hv[4];
#pragma unroll
    for (int uu = 0; uu < 4; ++uu) {
      float ig = sigf(acc[0][uu]);
      float fg = sigf(acc[1][uu]);
      float gg = tanhf(acc[2][uu]);
      float og = sigf(acc[3][uu]);
      cst[uu] = fg * cst[uu] + ig * gg;
      hv[uu]  = og * tanhf(cst[uu]);
      XH[(128 + j) * M + u4 + uu] = hv[uu];
    }
#pragma unroll
    for (int uu = 0; uu < 4; ++uu) {
      int n = nb + u4 + uu;
      if (dir == 0) {
        outF[((size_t)t * NN + n) * 128 + j] = hv[uu];
      } else {
        int len = lens[n];
        if (t < len) outB[((size_t)(len - 1 - t) * NN + n) * 128 + j] = hv[uu];
      }
    }
  }
}

// ---------------------------------------------------------------------------
// GEMM: rows x 128, K=256 over [INf|INb] with per-row validity mask (t<len).
// EPI 0: OUT = acc + bias.   EPI 1: also LayerNorm+tanh+attention scores.
// Block: 256 threads, 64-row tile, thread = 4 rows x 8 cols.
// ---------------------------------------------------------------------------
template <int EPI>
__global__ __launch_bounds__(256) void gemm_kernel(
    const float* __restrict__ INf, const float* __restrict__ INb,
    const int* __restrict__ lens,
    const float* __restrict__ WT, const float* __restrict__ bias,
    float* __restrict__ OUT,
    float* __restrict__ scores,
    const float* __restrict__ lng, const float* __restrict__ lnb,
    const float* __restrict__ attw, const float* __restrict__ attb,
    const int* __restrict__ units, int Nn)
{
  __shared__ float INS[64 * 64];
  __shared__ float WSg[64 * 128];
  __shared__ float red1[64 * 16];
  __shared__ float red2[64 * 16];
  __shared__ float rowm[64], rowr[64];

  int tid  = threadIdx.x;
  int row0 = blockIdx.x * 64;
  int t    = row0 / Nn, n0 = row0 % Nn;
  int rg   = tid & 15, cg = tid >> 4;

  float acc[4][8];
#pragma unroll
  for (int rr = 0; rr < 4; ++rr)
#pragma unroll
    for (int cc = 0; cc < 8; ++cc) acc[rr][cc] = 0.f;

  int r_load = tid & 63, kq = tid >> 6;
  int gn = n0 + r_load;
  int len = lens[gn];
  bool vrow = (t < len);
  const float* rowp_f = &INf[((size_t)t * Nn + gn) * 128];
  const float* rowp_b = &INb[((size_t)t * Nn + gn) * 128];

  for (int kc = 0; kc < 256; kc += 64) {
    __syncthreads();
#pragma unroll
    for (int x4 = 0; x4 < 4; ++x4) {
      int k = kc + kq * 16 + x4 * 4;
      float4 v;
      if (k < 128) v = *(const float4*)&rowp_f[k];
      else         v = *(const float4*)&rowp_b[k - 128];
      if (!vrow) v = make_float4(0.f, 0.f, 0.f, 0.f);
      int kk = k - kc;
      INS[(kk + 0) * 64 + r_load] = v.x;
      INS[(kk + 1) * 64 + r_load] = v.y;
      INS[(kk + 2) * 64 + r_load] = v.z;
      INS[(kk + 3) * 64 + r_load] = v.w;
    }
    for (int i = tid * 4; i < 64 * 128; i += 256 * 4)
      *(float4*)&WSg[i] = *(const float4*)&WT[kc * 128 + i];
    __syncthreads();
#pragma unroll 8
    for (int kk = 0; kk < 64; ++kk) {
      float4 a  = *(float4*)&INS[kk * 64 + 4 * rg];
      float4 b0 = *(float4*)&WSg[kk * 128 + 8 * cg];
      float4 b1 = *(float4*)&WSg[kk * 128 + 8 * cg + 4];
      float a4[4] = {a.x, a.y, a.z, a.w};
      float b8[8] = {b0.x, b0.y, b0.z, b0.w, b1.x, b1.y, b1.z, b1.w};
#pragma unroll
      for (int rr = 0; rr < 4; ++rr)
#pragma unroll
        for (int cc = 0; cc < 8; ++cc)
          acc[rr][cc] += a4[rr] * b8[cc];
    }
  }

  float bcol[8];
#pragma unroll
  for (int cc = 0; cc < 8; ++cc) bcol[cc] = bias[8 * cg + cc];
#pragma unroll
  for (int rr = 0; rr < 4; ++rr)
#pragma unroll
    for (int cc = 0; cc < 8; ++cc) acc[rr][cc] += bcol[cc];

#pragma unroll
  for (int rr = 0; rr < 4; ++rr) {
    int r = 4 * rg + rr;
    size_t o = ((size_t)t * Nn + n0 + r) * 128 + 8 * cg;
    *(float4*)&OUT[o]     = make_float4(acc[rr][0], acc[rr][1], acc[rr][2], acc[rr][3]);
    *(float4*)&OUT[o + 4] = make_float4(acc[rr][4], acc[rr][5], acc[rr][6], acc[rr][7]);
  }

  if (EPI == 1) {
#pragma unroll
    for (int rr = 0; rr < 4; ++rr) {
      float ps = 0.f, ps2 = 0.f;
#pragma unroll
      for (int cc = 0; cc < 8; ++cc) { ps += acc[rr][cc]; ps2 += acc[rr][cc] * acc[rr][cc]; }
      red1[(4 * rg + rr) * 16 + cg] = ps;
      red2[(4 * rg + rr) * 16 + cg] = ps2;
    }
    __syncthreads();
    if (tid < 64) {
      float s = 0.f, s2 = 0.f;
      for (int i = 0; i < 16; ++i) { s += red1[tid * 16 + i]; s2 += red2[tid * 16 + i]; }
      float m = s * (1.f / 128.f);
      float var = s2 * (1.f / 128.f) - m * m;
      rowm[tid] = m;
      rowr[tid] = rsqrtf(var + 1e-5f);
    }
    __syncthreads();
    float lg8[8], lb8[8], aw8[8];
#pragma unroll
    for (int cc = 0; cc < 8; ++cc) {
      lg8[cc] = lng[8 * cg + cc]; lb8[cc] = lnb[8 * cg + cc]; aw8[cc] = attw[8 * cg + cc];
    }
#pragma unroll
    for (int rr = 0; rr < 4; ++rr) {
      int r = 4 * rg + rr;
      float m = rowm[r], rs = rowr[r];
      float sp = 0.f;
#pragma unroll
      for (int cc = 0; cc < 8; ++cc) {
        float q = tanhf((acc[rr][cc] - m) * rs * lg8[cc] + lb8[cc]);
        sp += q * aw8[cc];
      }
      red1[r * 16 + cg] = sp;
    }
    __syncthreads();
    if (tid < 64) {
      float s = 0.f;
      for (int i = 0; i < 16; ++i) s += red1[tid * 16 + i];
      s += attb[0];
      int n = n0 + tid;
      if (units[t * NUNITS + n] == 0) s = -1e9f;
      scores[t * NUNITS + n] = s;
    }
  }
}

// ---------------------------------------------------------------------------
// Softmax over T=16 + attention-weighted pooling -> tok_feat[n][e]
// ---------------------------------------------------------------------------
__global__ __launch_bounds__(128) void softmax_feat_kernel(
    const float* __restrict__ scores, const float* __restrict__ out_lin,
    float* __restrict__ tok_feat)
{
  int n = blockIdx.x;
  int e = threadIdx.x;
  float s[T_TOKN];
  float m = -1e30f;
#pragma unroll
  for (int t = 0; t < T_TOKN; ++t) { s[t] = scores[t * NUNITS + n]; m = fmaxf(m, s[t]); }
  float sum = 0.f;
#pragma unroll
  for (int t = 0; t < T_TOKN; ++t) { s[t] = expf(s[t] - m); sum += s[t]; }
  float inv = 1.f / sum;
  float a = 0.f;
#pragma unroll
  for (int t = 0; t < T_TOKN; ++t)
    a += s[t] * inv * out_lin[((size_t)t * NUNITS + n) * 128 + e];
  tok_feat[n * 128 + e] = a;
}

// ---------------------------------------------------------------------------
extern "C" void kernel_launch(void* const* d_in, const int* in_sizes, int n_in,
                              void* d_out, int out_size, void* d_ws, size_t ws_size,
                              hipStream_t stream)
{
  const int*   units = (const int*)d_in[0];
  const int*   paths = (const int*)d_in[1];
  const int*   upd   = (const int*)d_in[2];
  const int*   ppd   = (const int*)d_in[3];
  const float* emb   = (const float*)d_in[4];
  const float* tWif  = (const float*)d_in[5];
  const float* tWhf  = (const float*)d_in[6];
  const float* tbf   = (const float*)d_in[7];
  const float* tWib  = (const float*)d_in[8];
  const float* tWhb  = (const float*)d_in[9];
  const float* tbb   = (const float*)d_in[10];
  const float* linW  = (const float*)d_in[11];
  const float* linb  = (const float*)d_in[12];
  const float* lng   = (const float*)d_in[13];
  const float* lnb   = (const float*)d_in[14];
  const float* attw  = (const float*)d_in[15];
  const float* attb  = (const float*)d_in[16];
  const float* pWif  = (const float*)d_in[17];
  const float* pWhf  = (const float*)d_in[18];
  const float* pbf   = (const float*)d_in[19];
  const float* pWib  = (const float*)d_in[20];
  const float* pWhb  = (const float*)d_in[21];
  const float* pbb   = (const float*)d_in[22];
  const float* ulW   = (const float*)d_in[23];
  const float* ulb   = (const float*)d_in[24];

  float* ws = (float*)d_ws;
  int*   ip = (int*)(ws + OFF_INT);
  if (ws_size < WS_FLOATS * sizeof(float)) return;  // scratch too small -> loud failure

  prep_kernel<<<2312, 256, 0, stream>>>(tWif, tWhf, tbf, tWib, tWhb, tbb,
                                        pWif, pWhf, pbf, pWib, pWhb, pbb,
                                        linW, ulW, ws);
  len_kernel<<<20, 256, 0, stream>>>(units, paths, upd, ppd, ip);

  lstm_kernel<0><<<dim3(256, 2), 512, 0, stream>>>(
      ws + OFF_WCTF, ws + OFF_WCTB, ws + OFF_BC, ws + OFF_BC + 512,
      emb, units, ip /*tok_len*/, nullptr, nullptr, nullptr,
      ws + OFF_OUTF, ws + OFF_OUTB);

  gemm_kernel<1><<<1024, 256, 0, stream>>>(
      ws + OFF_OUTF, ws + OFF_OUTB, ip /*tok_len*/, ws + OFF_LINWT, linb,
      ws + OFF_OUTLIN, ws + OFF_SCORES, lng, lnb, attw, attb, units, NUNITS);

  softmax_feat_kernel<<<4096, 128, 0, stream>>>(ws + OFF_SCORES, ws + OFF_OUTLIN,
                                                ws + OFF_TOKFEAT);

  lstm_kernel<1><<<dim3(128, 2), 256, 0, stream>>>(
      ws + OFF_WCPF, ws + OFF_WCPB, ws + OFF_BC + 1024, ws + OFF_BC + 1536,
      ws + OFF_TOKFEAT, paths, ip + 5120 /*p_len*/, ip + 4096 /*fe*/,
      ip + 6144 /*off_p*/, ip + 7168 /*un_p*/,
      ws + OFF_POUTF, ws + OFF_POUTB);

  gemm_kernel<0><<<512, 256, 0, stream>>>(
      ws + OFF_POUTF, ws + OFF_POUTB, ip + 5120 /*p_len*/, ws + OFF_ULWT, ulb,
      (float*)d_out, nullptr, nullptr, nullptr, nullptr, nullptr, nullptr, NPATHS);
}

// Round 2
// 401.985 us; speedup vs baseline: 7.6750x; 7.6750x over previous
//
#include <hip/hip_runtime.h>
#include <cstdint>
#include <cstddef>

// Problem constants
#define T_TOKN 16
#define NUNITS 4096
#define LPATH  32
#define NPATHS 1024
#define BNUM   8

typedef __attribute__((ext_vector_type(8))) short short8;   // 8 bf16 in 4 VGPRs
typedef __attribute__((ext_vector_type(4))) float f32x4;    // MFMA accumulator

// ws float offsets
enum : size_t {
  OFF_WFRAG  = 0,                        // 524288 bf16 (ushort) = 262144 floats: frag-swizzled [tf|tb|pf|pb]
  OFF_LINWT  = 262144,                   // lin_W^T [k][e] f32 256x128
  OFF_ULWT   = OFF_LINWT + 32768,
  OFF_OUTF   = OFF_ULWT + 32768,         // token fwd h, bf16 16x4096x128 -> 4194304 floats
  OFF_OUTB   = OFF_OUTF + 4194304,       // token bwd h (time-realigned), bf16
  OFF_OUTLIN = OFF_OUTB + 4194304,       // f32 16x4096x128
  OFF_SCORES = OFF_OUTLIN + 8388608,     // f32 16x4096
  OFF_TOKFEAT= OFF_SCORES + 65536,       // f32 4096x128
  OFF_POUTF  = OFF_TOKFEAT + 524288,     // path fwd h, bf16 32x1024x128 -> 2097152 floats
  OFF_POUTB  = OFF_POUTF + 2097152,
  OFF_INT    = OFF_POUTB + 2097152,      // ints: tok_len 4096 | fe 1024 | p_len 1024 | off_p 1024 | un_p 1024
  WS_FLOATS  = OFF_INT + 8192
};

static __device__ __forceinline__ unsigned short f2bf(float f) {
  union { float f; unsigned u; } v; v.f = f;
  unsigned r = v.u + 0x7fffu + ((v.u >> 16) & 1u);
  return (unsigned short)(r >> 16);
}
static __device__ __forceinline__ float bf2f(unsigned short h) {
  union { unsigned u; float f; } v; v.u = ((unsigned)h) << 16;
  return v.f;
}
static __device__ __forceinline__ float sigf(float x)      { return 1.f / (1.f + __expf(-x)); }
static __device__ __forceinline__ float tanhfast(float x)  { return 2.f / (1.f + __expf(-2.f * x)) - 1.f; }

// ---------------------------------------------------------------------------
// prep: build frag-swizzled bf16 weights.  For each matrix (tf,tb,pf,pb):
// frag (wv, ks, ct): 64 lanes x 8 bf16, element (lane,i) = Wc[g][k] with
// g = wv*64 + ct*16 + (lane&15),  k = ks*32 + (lane>>4)*8 + i,
// Wc[g][k] = k<128 ? Wi[g][k] : Wh[g][k-128].
// Also LINWT/ULWT f32 transposes [k][e].
// ---------------------------------------------------------------------------
__global__ void prep_kernel(
    const float* __restrict__ tWif, const float* __restrict__ tWhf,
    const float* __restrict__ tWib, const float* __restrict__ tWhb,
    const float* __restrict__ pWif, const float* __restrict__ pWhf,
    const float* __restrict__ pWib, const float* __restrict__ pWhb,
    const float* __restrict__ linW, const float* __restrict__ ulW,
    float* __restrict__ ws)
{
  int idx = blockIdx.x * 256 + threadIdx.x;
  unsigned short* wf = (unsigned short*)(ws + OFF_WFRAG);
  if (idx < 524288) {
    int mat = idx >> 17, rem = idx & 131071;
    int i  = rem & 7;
    int lane = (rem >> 3) & 63;
    int ct = (rem >> 9) & 3;
    int ks = (rem >> 11) & 7;
    int wv = (rem >> 14) & 7;
    int g = wv * 64 + ct * 16 + (lane & 15);
    int k = ks * 32 + ((lane >> 4) << 3) + i;
    const float* Wi; const float* Wh;
    switch (mat) {
      case 0: Wi = tWif; Wh = tWhf; break;
      case 1: Wi = tWib; Wh = tWhb; break;
      case 2: Wi = pWif; Wh = pWhf; break;
      default: Wi = pWib; Wh = pWhb; break;
    }
    float v = (k < 128) ? Wi[g * 128 + k] : Wh[g * 128 + (k - 128)];
    wf[idx] = f2bf(v);
  } else if (idx < 524288 + 65536) {
    int i2 = idx - 524288;
    int s = i2 >> 15, rem = i2 & 32767;
    int k = rem >> 7, e = rem & 127;
    const float* W = s ? ulW : linW;
    ws[OFF_LINWT + i2] = W[e * 256 + k];
  }
}

// ---------------------------------------------------------------------------
// Lengths / path metadata (unchanged from round 1 — verified correct)
// ---------------------------------------------------------------------------
__global__ void len_kernel(const int* __restrict__ units, const int* __restrict__ paths,
                           const int* __restrict__ upd, const int* __restrict__ ppd,
                           int* __restrict__ ip)
{
  int idx = blockIdx.x * 256 + threadIdx.x;
  int* tok_len = ip;
  int* fe_a    = ip + 4096;
  int* p_len   = ip + 5120;
  int* off_p   = ip + 6144;
  int* un_p    = ip + 7168;
  if (idx < 4096) {
    int len = T_TOKN;
    for (int t = 0; t < T_TOKN; ++t)
      if (units[t * NUNITS + idx] == 0) { len = t; break; }
    tok_len[idx] = len;
  } else if (idx < 5120) {
    int p = idx - 4096;
    int cum = 0; int d = BNUM - 1;
    for (int dd = 0; dd < BNUM; ++dd) {
      int c2 = cum + ppd[dd];
      if (p < c2) { d = dd; break; }
      cum = c2;
    }
    int off = 0;
    for (int dd = 0; dd < d; ++dd) off += upd[dd];
    int un = upd[d];
    off_p[p] = off; un_p[p] = un;
    int f = LPATH;
    for (int t = 0; t < LPATH; ++t)
      if (paths[t * NPATHS + p] == -1) { f = t; break; }
    fe_a[p] = f;
    int pl = LPATH;
    for (int t = 0; t < LPATH; ++t) {
      int v = paths[t * NPATHS + p];
      if ((t >= f) || (v < 0) || (v > un)) { pl = t; break; }
    }
    p_len[p] = pl;
  }
}

// ---------------------------------------------------------------------------
// MFMA BiLSTM.  Block = 8 waves, one direction, M sequences, loops all T.
// B ([Wi|Wh] slice, 64 gate-cols x 256 K, bf16) lives in 128 VGPRs/lane,
// loaded once from the pre-swizzled WFRAG area.  A = [x;h] bf16 tile in LDS.
// Gates exit MFMA in C-layout -> LDS -> pointwise (c stays fp32 in regs).
// MODE 0: token (gather emb[units], M=32).  MODE 1: path (gather tok_feat
// with keep-mask, M=8 padded to 16 tile rows).
// ---------------------------------------------------------------------------
template <int MODE>
__global__ __launch_bounds__(512, 2) void lstm_kernel(
    const unsigned short* __restrict__ wfragAll,
    const float* __restrict__ biasF, const float* __restrict__ biasB,
    const float* __restrict__ src,       // emb or tok_feat (f32)
    const int* __restrict__ idxsrc,      // units or paths
    const int* __restrict__ lens,        // tok_len or p_len
    const int* __restrict__ fe_a, const int* __restrict__ off_p, const int* __restrict__ un_p,
    unsigned short* __restrict__ outF, unsigned short* __restrict__ outB)
{
  constexpr int NN   = MODE ? NPATHS : NUNITS;
  constexpr int TT   = MODE ? LPATH : T_TOKN;
  constexpr int M    = MODE ? 8 : 32;     // real sequences per block
  constexpr int MR   = MODE ? 16 : 32;    // MFMA tile rows
  constexpr int NRT  = MR / 16;           // row-tiles
  constexpr int ASTR = 264;               // A-tile row stride (ushorts): 16B-aligned rows, conflict-free
  constexpr int GSTR = 514;               // gates row stride (f32): conflict-free C-writes
  constexpr int NU   = MODE ? 2 : 8;      // units per pointwise thread

  __shared__ unsigned short ash[MR * ASTR];  // [u][0:128)=x  [u][128:256)=h
  __shared__ float gates[MR * GSTR];         // [u][512 gate preacts]

  int tid  = threadIdx.x;
  int dir  = blockIdx.y;
  int n0   = blockIdx.x * M;
  int lane = tid & 63, wv = tid >> 6;

  // ---- load resident B fragments (coalesced: frag-swizzled layout) ----
  const unsigned short* wf = wfragAll + ((size_t)((MODE ? 2 : 0) + dir) * 8 + wv) * 16384;
  short8 bfr[32];                 // [ks*4 + ct]
#pragma unroll
  for (int f = 0; f < 32; ++f)
    bfr[f] = *(const short8*)(wf + (f * 64 + lane) * 8);

  // ---- zero h region (MODE 1: whole tile incl dummy rows) ----
  if (MODE == 0) {
    for (int i = tid; i < MR * 128; i += 512)
      ash[(i >> 7) * ASTR + 128 + (i & 127)] = 0;
  } else {
    for (int i = tid; i < MR * ASTR; i += 512) ash[i] = 0;
  }

  // ---- pointwise thread state ----
  int jj = tid & 127, ug = tid >> 7;
  const float* bcp = dir ? biasB : biasF;
  float b4[4];
#pragma unroll
  for (int q = 0; q < 4; ++q) b4[q] = bcp[q * 128 + jj];
  float cst[NU];
  int   ulen[NU];
#pragma unroll
  for (int i = 0; i < NU; ++i) {
    cst[i] = 0.f;
    int u = MODE ? (ug + 4 * i) : (ug * 8 + i);
    ulen[i] = lens[n0 + u];
  }

  // ---- gather thread state ----
  int gu, gk0;
  if (MODE == 0) { gu = tid >> 4; gk0 = (tid & 15) * 8; }
  else           { gu = tid >> 6; gk0 = (tid & 63) * 2; }
  int glen = lens[n0 + gu];
  int gfe = 0, goff = 0, gun = 0;
  if (MODE) { gfe = fe_a[n0 + gu]; goff = off_p[n0 + gu]; gun = un_p[n0 + gu]; }

  for (int t = 0; t < TT; ++t) {
    // ---- gather x(t) into A-tile (writes x region only) ----
    if (MODE == 0) {
      int tau = dir ? min(max(glen - 1 - t, 0), TT - 1) : t;
      int tok = idxsrc[tau * NN + (n0 + gu)];
      const float* xp = &src[(size_t)tok * 128 + gk0];
      float4 v0 = *(const float4*)xp;
      float4 v1 = *(const float4*)(xp + 4);
      short8 x8;
      x8[0] = (short)f2bf(v0.x); x8[1] = (short)f2bf(v0.y);
      x8[2] = (short)f2bf(v0.z); x8[3] = (short)f2bf(v0.w);
      x8[4] = (short)f2bf(v1.x); x8[5] = (short)f2bf(v1.y);
      x8[6] = (short)f2bf(v1.z); x8[7] = (short)f2bf(v1.w);
      *(short8*)&ash[gu * ASTR + gk0] = x8;
    } else {
      int tau = dir ? min(max(glen - 1 - t, 0), TT - 1) : t;
      int v = idxsrc[tau * NN + (n0 + gu)];
      bool keep = (tau < gfe) && (v >= 0) && (v < gun);
      float x0 = 0.f, x1 = 0.f;
      if (keep) {
        int gi = min(v + goff, NUNITS - 1);
        float2 xv = *(const float2*)&src[(size_t)gi * 128 + gk0];
        x0 = xv.x; x1 = xv.y;
      }
      unsigned pk = (unsigned)f2bf(x0) | ((unsigned)f2bf(x1) << 16);
      *(unsigned*)&ash[gu * ASTR + gk0] = pk;
    }
    __syncthreads();   // A-tile complete: x(t) + h(t-1); prior gates consumed

    // ---- MFMA gate GEMM: K=256, resident B ----
    f32x4 acc[NRT][4];
#pragma unroll
    for (int rt = 0; rt < NRT; ++rt)
#pragma unroll
      for (int ct = 0; ct < 4; ++ct) {
        f32x4 z = {0.f, 0.f, 0.f, 0.f};
        acc[rt][ct] = z;
      }
#pragma unroll
    for (int ks = 0; ks < 8; ++ks) {
      short8 afr[NRT];
#pragma unroll
      for (int rt = 0; rt < NRT; ++rt)
        afr[rt] = *(const short8*)&ash[(rt * 16 + (lane & 15)) * ASTR + ks * 32 + ((lane >> 4) << 3)];
#pragma unroll
      for (int rt = 0; rt < NRT; ++rt)
#pragma unroll
        for (int ct = 0; ct < 4; ++ct)
          acc[rt][ct] = __builtin_amdgcn_mfma_f32_16x16x32_bf16(
              afr[rt], bfr[ks * 4 + ct], acc[rt][ct], 0, 0, 0);
    }
    // ---- preacts -> LDS gates (C-layout: col=lane&15, row=quad*4+reg) ----
#pragma unroll
    for (int rt = 0; rt < NRT; ++rt)
#pragma unroll
      for (int ct = 0; ct < 4; ++ct) {
        int g = wv * 64 + ct * 16 + (lane & 15);
#pragma unroll
        for (int r = 0; r < 4; ++r) {
          int u = rt * 16 + ((lane >> 4) << 2) + r;
          gates[u * GSTR + g] = acc[rt][ct][r];
        }
      }
    __syncthreads();   // gates ready; all A-reads done

    // ---- pointwise LSTM update ----
#pragma unroll
    for (int i = 0; i < NU; ++i) {
      int u = MODE ? (ug + 4 * i) : (ug * 8 + i);
      int n = n0 + u;
      float p0 = gates[u * GSTR + jj]       + b4[0];
      float p1 = gates[u * GSTR + 128 + jj] + b4[1];
      float p2 = gates[u * GSTR + 256 + jj] + b4[2];
      float p3 = gates[u * GSTR + 384 + jj] + b4[3];
      float ig = sigf(p0), fg = sigf(p1), gg = tanhfast(p2), og = sigf(p3);
      float c = fg * cst[i] + ig * gg;
      cst[i] = c;
      float h = og * tanhfast(c);
      unsigned short hb = f2bf(h);
      ash[u * ASTR + 128 + jj] = hb;
      if (dir == 0) {
        outF[((size_t)t * NN + n) * 128 + jj] = hb;
      } else {
        int L = ulen[i];
        if (t < L) outB[((size_t)(L - 1 - t) * NN + n) * 128 + jj] = hb;
      }
    }
    // next-iter gather writes only the x region (disjoint from h/gates) -> safe
  }
}

// ---------------------------------------------------------------------------
// GEMM: rows x 128, K=256 over bf16 [INf|INb] with per-row validity (t<len).
// EPI 0: OUT = acc + bias.   EPI 1: also LayerNorm+tanh+attention scores.
// ---------------------------------------------------------------------------
template <int EPI>
__global__ __launch_bounds__(256) void gemm_kernel(
    const unsigned short* __restrict__ INf, const unsigned short* __restrict__ INb,
    const int* __restrict__ lens,
    const float* __restrict__ WT, const float* __restrict__ bias,
    float* __restrict__ OUT,
    float* __restrict__ scores,
    const float* __restrict__ lng, const float* __restrict__ lnb,
    const float* __restrict__ attw, const float* __restrict__ attb,
    const int* __restrict__ units, int Nn)
{
  __shared__ float INS[64 * 64];
  __shared__ float WSg[64 * 128];
  __shared__ float red1[64 * 16];
  __shared__ float red2[64 * 16];
  __shared__ float rowm[64], rowr[64];

  int tid  = threadIdx.x;
  int row0 = blockIdx.x * 64;
  int t    = row0 / Nn, n0 = row0 % Nn;
  int rg   = tid & 15, cg = tid >> 4;

  float acc[4][8];
#pragma unroll
  for (int rr = 0; rr < 4; ++rr)
#pragma unroll
    for (int cc = 0; cc < 8; ++cc) acc[rr][cc] = 0.f;

  int r_load = tid & 63, kq = tid >> 6;
  int gn = n0 + r_load;
  int len = lens[gn];
  bool vrow = (t < len);
  const unsigned short* rowp_f = &INf[((size_t)t * Nn + gn) * 128];
  const unsigned short* rowp_b = &INb[((size_t)t * Nn + gn) * 128];

  for (int kc = 0; kc < 256; kc += 64) {
    __syncthreads();
#pragma unroll
    for (int x4 = 0; x4 < 4; ++x4) {
      int k = kc + kq * 16 + x4 * 4;
      ushort4 uv;
      if (k < 128) uv = *(const ushort4*)&rowp_f[k];
      else         uv = *(const ushort4*)&rowp_b[k - 128];
      float4 v = make_float4(bf2f(uv.x), bf2f(uv.y), bf2f(uv.z), bf2f(uv.w));
      if (!vrow) v = make_float4(0.f, 0.f, 0.f, 0.f);
      int kk = k - kc;
      INS[(kk + 0) * 64 + r_load] = v.x;
      INS[(kk + 1) * 64 + r_load] = v.y;
      INS[(kk + 2) * 64 + r_load] = v.z;
      INS[(kk + 3) * 64 + r_load] = v.w;
    }
    for (int i = tid * 4; i < 64 * 128; i += 256 * 4)
      *(float4*)&WSg[i] = *(const float4*)&WT[kc * 128 + i];
    __syncthreads();
#pragma unroll 8
    for (int kk = 0; kk < 64; ++kk) {
      float4 a  = *(float4*)&INS[kk * 64 + 4 * rg];
      float4 b0 = *(float4*)&WSg[kk * 128 + 8 * cg];
      float4 b1 = *(float4*)&WSg[kk * 128 + 8 * cg + 4];
      float a4[4] = {a.x, a.y, a.z, a.w};
      float b8[8] = {b0.x, b0.y, b0.z, b0.w, b1.x, b1.y, b1.z, b1.w};
#pragma unroll
      for (int rr = 0; rr < 4; ++rr)
#pragma unroll
        for (int cc = 0; cc < 8; ++cc)
          acc[rr][cc] += a4[rr] * b8[cc];
    }
  }

  float bcol[8];
#pragma unroll
  for (int cc = 0; cc < 8; ++cc) bcol[cc] = bias[8 * cg + cc];
#pragma unroll
  for (int rr = 0; rr < 4; ++rr)
#pragma unroll
    for (int cc = 0; cc < 8; ++cc) acc[rr][cc] += bcol[cc];

#pragma unroll
  for (int rr = 0; rr < 4; ++rr) {
    int r = 4 * rg + rr;
    size_t o = ((size_t)t * Nn + n0 + r) * 128 + 8 * cg;
    *(float4*)&OUT[o]     = make_float4(acc[rr][0], acc[rr][1], acc[rr][2], acc[rr][3]);
    *(float4*)&OUT[o + 4] = make_float4(acc[rr][4], acc[rr][5], acc[rr][6], acc[rr][7]);
  }

  if (EPI == 1) {
#pragma unroll
    for (int rr = 0; rr < 4; ++rr) {
      float ps = 0.f, ps2 = 0.f;
#pragma unroll
      for (int cc = 0; cc < 8; ++cc) { ps += acc[rr][cc]; ps2 += acc[rr][cc] * acc[rr][cc]; }
      red1[(4 * rg + rr) * 16 + cg] = ps;
      red2[(4 * rg + rr) * 16 + cg] = ps2;
    }
    __syncthreads();
    if (tid < 64) {
      float s = 0.f, s2 = 0.f;
      for (int i = 0; i < 16; ++i) { s += red1[tid * 16 + i]; s2 += red2[tid * 16 + i]; }
      float m = s * (1.f / 128.f);
      float var = s2 * (1.f / 128.f) - m * m;
      rowm[tid] = m;
      rowr[tid] = rsqrtf(var + 1e-5f);
    }
    __syncthreads();
    float lg8[8], lb8[8], aw8[8];
#pragma unroll
    for (int cc = 0; cc < 8; ++cc) {
      lg8[cc] = lng[8 * cg + cc]; lb8[cc] = lnb[8 * cg + cc]; aw8[cc] = attw[8 * cg + cc];
    }
#pragma unroll
    for (int rr = 0; rr < 4; ++rr) {
      int r = 4 * rg + rr;
      float m = rowm[r], rs = rowr[r];
      float sp = 0.f;
#pragma unroll
      for (int cc = 0; cc < 8; ++cc) {
        float q = tanhf((acc[rr][cc] - m) * rs * lg8[cc] + lb8[cc]);
        sp += q * aw8[cc];
      }
      red1[r * 16 + cg] = sp;
    }
    __syncthreads();
    if (tid < 64) {
      float s = 0.f;
      for (int i = 0; i < 16; ++i) s += red1[tid * 16 + i];
      s += attb[0];
      int n = n0 + tid;
      if (units[t * NUNITS + n] == 0) s = -1e9f;
      scores[t * NUNITS + n] = s;
    }
  }
}

// ---------------------------------------------------------------------------
// Softmax over T=16 + attention-weighted pooling -> tok_feat[n][e]
// ---------------------------------------------------------------------------
__global__ __launch_bounds__(128) void softmax_feat_kernel(
    const float* __restrict__ scores, const float* __restrict__ out_lin,
    float* __restrict__ tok_feat)
{
  int n = blockIdx.x;
  int e = threadIdx.x;
  float s[T_TOKN];
  float m = -1e30f;
#pragma unroll
  for (int t = 0; t < T_TOKN; ++t) { s[t] = scores[t * NUNITS + n]; m = fmaxf(m, s[t]); }
  float sum = 0.f;
#pragma unroll
  for (int t = 0; t < T_TOKN; ++t) { s[t] = expf(s[t] - m); sum += s[t]; }
  float inv = 1.f / sum;
  float a = 0.f;
#pragma unroll
  for (int t = 0; t < T_TOKN; ++t)
    a += s[t] * inv * out_lin[((size_t)t * NUNITS + n) * 128 + e];
  tok_feat[n * 128 + e] = a;
}

// ---------------------------------------------------------------------------
extern "C" void kernel_launch(void* const* d_in, const int* in_sizes, int n_in,
                              void* d_out, int out_size, void* d_ws, size_t ws_size,
                              hipStream_t stream)
{
  const int*   units = (const int*)d_in[0];
  const int*   paths = (const int*)d_in[1];
  const int*   upd   = (const int*)d_in[2];
  const int*   ppd   = (const int*)d_in[3];
  const float* emb   = (const float*)d_in[4];
  const float* tWif  = (const float*)d_in[5];
  const float* tWhf  = (const float*)d_in[6];
  const float* tbf   = (const float*)d_in[7];
  const float* tWib  = (const float*)d_in[8];
  const float* tWhb  = (const float*)d_in[9];
  const float* tbb   = (const float*)d_in[10];
  const float* linW  = (const float*)d_in[11];
  const float* linb  = (const float*)d_in[12];
  const float* lng   = (const float*)d_in[13];
  const float* lnb   = (const float*)d_in[14];
  const float* attw  = (const float*)d_in[15];
  const float* attb  = (const float*)d_in[16];
  const float* pWif  = (const float*)d_in[17];
  const float* pWhf  = (const float*)d_in[18];
  const float* pbf   = (const float*)d_in[19];
  const float* pWib  = (const float*)d_in[20];
  const float* pWhb  = (const float*)d_in[21];
  const float* pbb   = (const float*)d_in[22];
  const float* ulW   = (const float*)d_in[23];
  const float* ulb   = (const float*)d_in[24];

  float* ws = (float*)d_ws;
  int*   ip = (int*)(ws + OFF_INT);
  if (ws_size < WS_FLOATS * sizeof(float)) return;

  unsigned short* wfrag = (unsigned short*)(ws + OFF_WFRAG);
  unsigned short* OUTF  = (unsigned short*)(ws + OFF_OUTF);
  unsigned short* OUTB  = (unsigned short*)(ws + OFF_OUTB);
  unsigned short* POUTF = (unsigned short*)(ws + OFF_POUTF);
  unsigned short* POUTB = (unsigned short*)(ws + OFF_POUTB);

  prep_kernel<<<2304, 256, 0, stream>>>(tWif, tWhf, tWib, tWhb,
                                        pWif, pWhf, pWib, pWhb,
                                        linW, ulW, ws);
  len_kernel<<<20, 256, 0, stream>>>(units, paths, upd, ppd, ip);

  lstm_kernel<0><<<dim3(128, 2), 512, 0, stream>>>(
      wfrag, tbf, tbb, emb, units, ip /*tok_len*/, nullptr, nullptr, nullptr,
      OUTF, OUTB);

  gemm_kernel<1><<<1024, 256, 0, stream>>>(
      OUTF, OUTB, ip /*tok_len*/, ws + OFF_LINWT, linb,
      ws + OFF_OUTLIN, ws + OFF_SCORES, lng, lnb, attw, attb, units, NUNITS);

  softmax_feat_kernel<<<4096, 128, 0, stream>>>(ws + OFF_SCORES, ws + OFF_OUTLIN,
                                                ws + OFF_TOKFEAT);

  lstm_kernel<1><<<dim3(128, 2), 512, 0, stream>>>(
      wfrag, pbf, pbb, ws + OFF_TOKFEAT, paths, ip + 5120 /*p_len*/,
      ip + 4096 /*fe*/, ip + 6144 /*off_p*/, ip + 7168 /*un_p*/,
      POUTF, POUTB);

  gemm_kernel<0><<<512, 256, 0, stream>>>(
      POUTF, POUTB, ip + 5120 /*p_len*/, ws + OFF_ULWT, ulb,
      (float*)d_out, nullptr, nullptr, nullptr, nullptr, nullptr, nullptr, NPATHS);
}

// Round 5
// 340.609 us; speedup vs baseline: 9.0580x; 1.1802x over previous
//
#include <hip/hip_runtime.h>
#include <cstdint>
#include <cstddef>

// Problem constants
#define T_TOKN 16
#define NUNITS 4096
#define LPATH  32
#define NPATHS 1024
#define BNUM   8

typedef __attribute__((ext_vector_type(8))) short short8;   // 8 bf16 in 4 VGPRs
typedef __attribute__((ext_vector_type(4))) short short4x;  // 4 bf16 in 2 VGPRs
typedef __attribute__((ext_vector_type(4))) float f32x4;    // MFMA accumulator

// ws float offsets
enum : size_t {
  OFF_WFRAG   = 0,                        // 524288 ushort: lstm W frags [tf|tb|pf|pb]
  OFF_LINFRAG = 262144,                   // 65536 ushort: lin/ul B-frags
  OFF_OUTF    = 294912,                   // token fwd h, bf16 16x4096x128
  OFF_OUTB    = OFF_OUTF + 4194304,       // token bwd h (time-realigned), bf16
  OFF_OUTLIN  = OFF_OUTB + 4194304,       // f32 16x4096x128
  OFF_SCORES  = OFF_OUTLIN + 8388608,     // f32 16x4096
  OFF_TOKFEAT = OFF_SCORES + 65536,       // f32 4096x128
  OFF_POUTF   = OFF_TOKFEAT + 524288,     // path fwd h, bf16 32x1024x128
  OFF_POUTB   = OFF_POUTF + 2097152,
  OFF_INT     = OFF_POUTB + 2097152,      // ints: tok_len 4096 | fe 1024 | p_len 1024 | off_p 1024 | un_p 1024
  WS_FLOATS   = OFF_INT + 8192
};

static __device__ __forceinline__ unsigned short f2bf(float f) {
  union { float f; unsigned u; } v; v.f = f;
  unsigned r = v.u + 0x7fffu + ((v.u >> 16) & 1u);
  return (unsigned short)(r >> 16);
}
static __device__ __forceinline__ float sigf(float x)      { return 1.f / (1.f + __expf(-x)); }
static __device__ __forceinline__ float tanhfast(float x)  { return 2.f / (1.f + __expf(-2.f * x)) - 1.f; }

// ---------------------------------------------------------------------------
// prep: (a) lstm W frags: element (mat, wv8, ks, ct, lane, i) =
//   Wc[g][k], g = wv8*64 + ct*16 + (lane&15), k = ks*32 + (lane>>4)*8 + i.
// (b) lin/ul MFMA B-frags: element (mat, ct, ks, lane, i) =
//   W[e][k], e = ct*16 + (lane&15), k = ks*32 + (lane>>4)*8 + i.
// ---------------------------------------------------------------------------
__global__ void prep_kernel(
    const float* __restrict__ tWif, const float* __restrict__ tWhf,
    const float* __restrict__ tWib, const float* __restrict__ tWhb,
    const float* __restrict__ pWif, const float* __restrict__ pWhf,
    const float* __restrict__ pWib, const float* __restrict__ pWhb,
    const float* __restrict__ linW, const float* __restrict__ ulW,
    float* __restrict__ ws)
{
  int idx = blockIdx.x * 256 + threadIdx.x;
  if (idx < 524288) {
    unsigned short* wf = (unsigned short*)(ws + OFF_WFRAG);
    int mat = idx >> 17, rem = idx & 131071;
    int i  = rem & 7;
    int lane = (rem >> 3) & 63;
    int ct = (rem >> 9) & 3;
    int ks = (rem >> 11) & 7;
    int wv = (rem >> 14) & 7;
    int g = wv * 64 + ct * 16 + (lane & 15);
    int k = ks * 32 + ((lane >> 4) << 3) + i;
    const float* Wi; const float* Wh;
    switch (mat) {
      case 0: Wi = tWif; Wh = tWhf; break;
      case 1: Wi = tWib; Wh = tWhb; break;
      case 2: Wi = pWif; Wh = pWhf; break;
      default: Wi = pWib; Wh = pWhb; break;
    }
    float v = (k < 128) ? Wi[g * 128 + k] : Wh[g * 128 + (k - 128)];
    wf[idx] = f2bf(v);
  } else if (idx < 524288 + 65536) {
    unsigned short* lf = (unsigned short*)(ws + OFF_LINFRAG);
    int i2 = idx - 524288;
    int mat = i2 >> 15, rem = i2 & 32767;
    int i  = rem & 7;
    int lane = (rem >> 3) & 63;
    int ks = (rem >> 9) & 7;
    int ct = (rem >> 12) & 7;
    int e = ct * 16 + (lane & 15);
    int k = ks * 32 + ((lane >> 4) << 3) + i;
    const float* W = mat ? ulW : linW;
    lf[i2] = f2bf(W[e * 256 + k]);
  }
}

// ---------------------------------------------------------------------------
// Lengths / path metadata
// ---------------------------------------------------------------------------
__global__ void len_kernel(const int* __restrict__ units, const int* __restrict__ paths,
                           const int* __restrict__ upd, const int* __restrict__ ppd,
                           int* __restrict__ ip)
{
  int idx = blockIdx.x * 256 + threadIdx.x;
  int* tok_len = ip;
  int* fe_a    = ip + 4096;
  int* p_len   = ip + 5120;
  int* off_p   = ip + 6144;
  int* un_p    = ip + 7168;
  if (idx < 4096) {
    int len = T_TOKN;
    for (int t = 0; t < T_TOKN; ++t)
      if (units[t * NUNITS + idx] == 0) { len = t; break; }
    tok_len[idx] = len;
  } else if (idx < 5120) {
    int p = idx - 4096;
    int cum = 0; int d = BNUM - 1;
    for (int dd = 0; dd < BNUM; ++dd) {
      int c2 = cum + ppd[dd];
      if (p < c2) { d = dd; break; }
      cum = c2;
    }
    int off = 0;
    for (int dd = 0; dd < d; ++dd) off += upd[dd];
    int un = upd[d];
    off_p[p] = off; un_p[p] = un;
    int f = LPATH;
    for (int t = 0; t < LPATH; ++t)
      if (paths[t * NPATHS + p] == -1) { f = t; break; }
    fe_a[p] = f;
    int pl = LPATH;
    for (int t = 0; t < LPATH; ++t) {
      int v = paths[t * NPATHS + p];
      if ((t >= f) || (v < 0) || (v > un)) { pl = t; break; }
    }
    p_len[p] = pl;
  }
}

// ---------------------------------------------------------------------------
// MFMA BiLSTM, 16-wave blocks.  Each wave owns a 32-gate-column B slice
// (64 VGPR/lane, resident).  A = [x;h] bf16 tile in LDS.  2 barriers/step
// (+1 after init: the zero-init and first gather both write the x region —
// without the barrier a late wave's zero could clobber gathered x, the
// round-4 replay race).
// MODE 0: token (emb gather, M=32).  MODE 1: path (tok_feat gather, M=8).
// ---------------------------------------------------------------------------
template <int MODE>
__global__ __launch_bounds__(1024, 4) void lstm_kernel(
    const unsigned short* __restrict__ wfragAll,
    const float* __restrict__ biasF, const float* __restrict__ biasB,
    const float* __restrict__ src,       // emb or tok_feat (f32)
    const int* __restrict__ idxsrc,      // units or paths
    const int* __restrict__ lens,        // tok_len or p_len
    const int* __restrict__ fe_a, const int* __restrict__ off_p, const int* __restrict__ un_p,
    unsigned short* __restrict__ outF, unsigned short* __restrict__ outB)
{
  constexpr int NN   = MODE ? NPATHS : NUNITS;
  constexpr int TT   = MODE ? LPATH : T_TOKN;
  constexpr int M    = MODE ? 8 : 32;     // real sequences per block
  constexpr int MR   = MODE ? 16 : 32;    // MFMA tile rows
  constexpr int NRT  = MR / 16;
  constexpr int ASTR = 264;               // A-tile row stride (ushorts)
  constexpr int GSTR = 514;               // gates row stride (f32)
  constexpr int NU   = MODE ? 1 : 4;      // units per pointwise thread

  __shared__ unsigned short ash[MR * ASTR];  // [u][0:128)=x  [u][128:256)=h
  __shared__ float gates[MR * GSTR];

  int tid  = threadIdx.x;
  int dir  = blockIdx.y;
  int n0   = blockIdx.x * M;
  int lane = tid & 63, wv = tid >> 6;       // wv in [0,16)

  // ---- resident B fragments: wave wv covers gates [wv*32, wv*32+32) ----
  const unsigned short* wbase =
      wfragAll + (size_t)((MODE ? 2 : 0) + dir) * 131072;
  int wv8 = wv >> 1;
  short8 bfr[8][2];
#pragma unroll
  for (int ks = 0; ks < 8; ++ks)
#pragma unroll
    for (int c2 = 0; c2 < 2; ++c2) {
      int ct = ((wv & 1) << 1) | c2;
      bfr[ks][c2] = *(const short8*)&wbase[((((wv8 * 8 + ks) * 4 + ct) * 64) + lane) * 8];
    }

  // ---- zero LDS (h region; MODE 1: whole tile incl dummy rows) ----
  if (MODE == 0) {
    for (int i = tid; i < MR * 128; i += 1024)
      ash[(i >> 7) * ASTR + 128 + (i & 127)] = 0;
  } else {
    for (int i = tid; i < MR * ASTR; i += 1024) ash[i] = 0;
  }
  __syncthreads();   // init writes must complete before first gather (race fix)

  // ---- pointwise thread state ----
  int jj = tid & 127, ug = tid >> 7;        // ug in [0,8)
  const float* bcp = dir ? biasB : biasF;
  float b4[4];
#pragma unroll
  for (int q = 0; q < 4; ++q) b4[q] = bcp[q * 128 + jj];
  float cst[NU];
  int   ulen[NU];
#pragma unroll
  for (int i = 0; i < NU; ++i) {
    cst[i] = 0.f;
    int u = ug * NU + i;
    ulen[i] = lens[n0 + u];
  }

  // ---- gather thread state ----
  int gu, gk0;
  if (MODE == 0) { gu = tid >> 5; gk0 = (tid & 31) * 4; }   // 32 rows x 32 thr
  else           { gu = tid >> 7; gk0 = tid & 127; }        // 8 rows x 128 thr
  int glen = lens[n0 + gu];
  int gfe = 0, goff = 0, gun = 0;
  if (MODE) { gfe = fe_a[n0 + gu]; goff = off_p[n0 + gu]; gun = un_p[n0 + gu]; }

  for (int t = 0; t < TT; ++t) {
    // ---- gather x(t) into A-tile x region ----
    if (MODE == 0) {
      int tau = dir ? min(max(glen - 1 - t, 0), TT - 1) : t;
      int tok = idxsrc[tau * NN + (n0 + gu)];
      float4 v = *(const float4*)&src[(size_t)tok * 128 + gk0];
      short4x x4;
      x4[0] = (short)f2bf(v.x); x4[1] = (short)f2bf(v.y);
      x4[2] = (short)f2bf(v.z); x4[3] = (short)f2bf(v.w);
      *(short4x*)&ash[gu * ASTR + gk0] = x4;
    } else {
      int tau = dir ? min(max(glen - 1 - t, 0), TT - 1) : t;
      int v = idxsrc[tau * NN + (n0 + gu)];
      bool keep = (tau < gfe) && (v >= 0) && (v < gun);
      float x0 = 0.f;
      if (keep) {
        int gi = min(v + goff, NUNITS - 1);
        x0 = src[(size_t)gi * 128 + gk0];
      }
      ash[gu * ASTR + gk0] = f2bf(x0);
    }
    __syncthreads();   // A-tile complete: x(t) + h(t-1)

    // ---- MFMA gate GEMM: K=256, resident B ----
    f32x4 acc[NRT][2];
#pragma unroll
    for (int rt = 0; rt < NRT; ++rt)
#pragma unroll
      for (int c2 = 0; c2 < 2; ++c2) {
        f32x4 z = {0.f, 0.f, 0.f, 0.f};
        acc[rt][c2] = z;
      }
#pragma unroll
    for (int ks = 0; ks < 8; ++ks) {
      short8 afr[NRT];
#pragma unroll
      for (int rt = 0; rt < NRT; ++rt)
        afr[rt] = *(const short8*)&ash[(rt * 16 + (lane & 15)) * ASTR + ks * 32 + ((lane >> 4) << 3)];
#pragma unroll
      for (int rt = 0; rt < NRT; ++rt)
#pragma unroll
        for (int c2 = 0; c2 < 2; ++c2)
          acc[rt][c2] = __builtin_amdgcn_mfma_f32_16x16x32_bf16(
              afr[rt], bfr[ks][c2], acc[rt][c2], 0, 0, 0);
    }
    // ---- preacts -> LDS gates (C-layout: col=lane&15, row=quad*4+reg) ----
#pragma unroll
    for (int rt = 0; rt < NRT; ++rt)
#pragma unroll
      for (int c2 = 0; c2 < 2; ++c2) {
        int g = wv * 32 + c2 * 16 + (lane & 15);
#pragma unroll
        for (int r = 0; r < 4; ++r) {
          int u = rt * 16 + ((lane >> 4) << 2) + r;
          gates[u * GSTR + g] = acc[rt][c2][r];
        }
      }
    __syncthreads();   // gates ready; all A-tile reads done

    // ---- pointwise LSTM update ----
#pragma unroll
    for (int i = 0; i < NU; ++i) {
      int u = ug * NU + i;
      int n = n0 + u;
      float p0 = gates[u * GSTR + jj]       + b4[0];
      float p1 = gates[u * GSTR + 128 + jj] + b4[1];
      float p2 = gates[u * GSTR + 256 + jj] + b4[2];
      float p3 = gates[u * GSTR + 384 + jj] + b4[3];
      float ig = sigf(p0), fg = sigf(p1), gg = tanhfast(p2), og = sigf(p3);
      float c = fg * cst[i] + ig * gg;
      cst[i] = c;
      float h = og * tanhfast(c);
      unsigned short hb = f2bf(h);
      ash[u * ASTR + 128 + jj] = hb;
      if (dir == 0) {
        outF[((size_t)t * NN + n) * 128 + jj] = hb;
      } else {
        int L = ulen[i];
        // t < L: realigned slot L-1-t in [0,L).  t >= L: slot t in [L,TT)
        // is exactly the otherwise-unwritten one -> zero-fill (kills poison).
        if (t < L) outB[((size_t)(L - 1 - t) * NN + n) * 128 + jj] = hb;
        else       outB[((size_t)t * NN + n) * 128 + jj] = 0;
      }
    }
    // next-iter gather writes only x region (disjoint from h/gates) -> safe
  }
}

// ---------------------------------------------------------------------------
// MFMA GEMM: rows x 128, K=256, A = bf16 [INf|INb] from global, B resident
// (64 VGPR/lane, 4 waves cover 128 cols).  C+bias -> LDS tile -> epilogue.
// EPI 0: row-validity mask on A (invalid rows -> OUT = bias), f32 store.
// EPI 1: store OUT + fused LayerNorm+tanh+attention scores (no mask needed:
//        invalid rows get softmax weight exactly 0 downstream).
// ---------------------------------------------------------------------------
template <int EPI>
__global__ __launch_bounds__(256) void gemm_mfma(
    const unsigned short* __restrict__ INf, const unsigned short* __restrict__ INb,
    const int* __restrict__ lens,
    const unsigned short* __restrict__ Bfrag, const float* __restrict__ bias,
    float* __restrict__ OUT, float* __restrict__ scores,
    const float* __restrict__ lng, const float* __restrict__ lnb,
    const float* __restrict__ attw, const float* __restrict__ attb,
    const int* __restrict__ units, int Nn)
{
  constexpr int OSTR = 132;
  __shared__ float outs[64 * OSTR];
  __shared__ float red1[256];
  __shared__ float red2[256];
  __shared__ float rowm[64], rowr[64];
  __shared__ float awsh[128], lgsh[128], lbsh[128];

  int tid = threadIdx.x, lane = tid & 63, wv = tid >> 6;
  int row0 = blockIdx.x * 64;
  int t = row0 / Nn, n0 = row0 % Nn;   // 64-row blocks never straddle t

  if (EPI == 1 && tid < 128) {
    awsh[tid] = attw[tid]; lgsh[tid] = lng[tid]; lbsh[tid] = lnb[tid];
  }

  // resident B: wave wv covers cols [wv*32, wv*32+32)
  short8 bfr[8][2];
#pragma unroll
  for (int ks = 0; ks < 8; ++ks)
#pragma unroll
    for (int c2 = 0; c2 < 2; ++c2) {
      int ct = wv * 2 + c2;
      bfr[ks][c2] = *(const short8*)&Bfrag[(((ct * 8 + ks) * 64) + lane) * 8];
    }

  int rb = lane & 15;
  int koq = (lane >> 4) << 3;
  bool val[4];
#pragma unroll
  for (int rt = 0; rt < 4; ++rt)
    val[rt] = (EPI == 1) ? true : (t < lens[n0 + rt * 16 + rb]);

  f32x4 acc[4][2];
#pragma unroll
  for (int rt = 0; rt < 4; ++rt)
#pragma unroll
    for (int c2 = 0; c2 < 2; ++c2) {
      f32x4 z = {0.f, 0.f, 0.f, 0.f};
      acc[rt][c2] = z;
    }

#pragma unroll
  for (int ks = 0; ks < 8; ++ks) {
    const unsigned short* P = (ks < 4) ? INf : INb;
    int koff = (ks & 3) * 32 + koq;
#pragma unroll
    for (int rt = 0; rt < 4; ++rt) {
      short8 a = {0, 0, 0, 0, 0, 0, 0, 0};
      if (val[rt])
        a = *(const short8*)&P[((size_t)(row0 + rt * 16 + rb)) * 128 + koff];
#pragma unroll
      for (int c2 = 0; c2 < 2; ++c2)
        acc[rt][c2] = __builtin_amdgcn_mfma_f32_16x16x32_bf16(
            a, bfr[ks][c2], acc[rt][c2], 0, 0, 0);
    }
  }

  // C + bias -> LDS
  float bc[2];
#pragma unroll
  for (int c2 = 0; c2 < 2; ++c2) bc[c2] = bias[wv * 32 + c2 * 16 + rb];
#pragma unroll
  for (int rt = 0; rt < 4; ++rt)
#pragma unroll
    for (int c2 = 0; c2 < 2; ++c2) {
      int col = wv * 32 + c2 * 16 + rb;
      int ub  = rt * 16 + ((lane >> 4) << 2);
#pragma unroll
      for (int r = 0; r < 4; ++r)
        outs[(ub + r) * OSTR + col] = acc[rt][c2][r] + bc[c2];
    }
  __syncthreads();

  int row = tid >> 2, seg = tid & 3;
  const float* rp = &outs[row * OSTR + seg * 32];
  size_t go = ((size_t)(row0 + row)) * 128 + seg * 32;

  if (EPI == 0) {
#pragma unroll
    for (int x = 0; x < 8; ++x)
      *(f32x4*)&OUT[go + x * 4] = *(const f32x4*)&rp[x * 4];
  } else {
    f32x4 v[8];
    float s = 0.f, s2 = 0.f;
#pragma unroll
    for (int x = 0; x < 8; ++x) {
      v[x] = *(const f32x4*)&rp[x * 4];
#pragma unroll
      for (int c = 0; c < 4; ++c) { s += v[x][c]; s2 += v[x][c] * v[x][c]; }
    }
    red1[tid] = s; red2[tid] = s2;
    __syncthreads();
    if (tid < 64) {
      float a = red1[tid * 4] + red1[tid * 4 + 1] + red1[tid * 4 + 2] + red1[tid * 4 + 3];
      float b = red2[tid * 4] + red2[tid * 4 + 1] + red2[tid * 4 + 2] + red2[tid * 4 + 3];
      float m = a * (1.f / 128.f);
      float var = b * (1.f / 128.f) - m * m;
      rowm[tid] = m;
      rowr[tid] = rsqrtf(var + 1e-5f);
    }
    __syncthreads();
    float m = rowm[row], rs = rowr[row];
    float sp = 0.f;
#pragma unroll
    for (int x = 0; x < 8; ++x) {
#pragma unroll
      for (int c = 0; c < 4; ++c) {
        int col = seg * 32 + x * 4 + c;
        float q = tanhfast((v[x][c] - m) * rs * lgsh[col] + lbsh[col]);
        sp += q * awsh[col];
      }
      *(f32x4*)&OUT[go + x * 4] = v[x];
    }
    red1[tid] = sp;
    __syncthreads();
    if (tid < 64) {
      float s3 = red1[tid * 4] + red1[tid * 4 + 1] + red1[tid * 4 + 2] + red1[tid * 4 + 3]
               + attb[0];
      int n = n0 + tid;
      if (units[t * NUNITS + n] == 0) s3 = -1e9f;
      scores[t * NUNITS + n] = s3;
    }
  }
}

// ---------------------------------------------------------------------------
// Softmax over T=16 + attention-weighted pooling -> tok_feat[n][e]
// ---------------------------------------------------------------------------
__global__ __launch_bounds__(128) void softmax_feat_kernel(
    const float* __restrict__ scores, const float* __restrict__ out_lin,
    float* __restrict__ tok_feat)
{
  int n = blockIdx.x;
  int e = threadIdx.x;
  float s[T_TOKN];
  float m = -1e30f;
#pragma unroll
  for (int t = 0; t < T_TOKN; ++t) { s[t] = scores[t * NUNITS + n]; m = fmaxf(m, s[t]); }
  float sum = 0.f;
#pragma unroll
  for (int t = 0; t < T_TOKN; ++t) { s[t] = expf(s[t] - m); sum += s[t]; }
  float inv = 1.f / sum;
  float a = 0.f;
#pragma unroll
  for (int t = 0; t < T_TOKN; ++t)
    a += s[t] * inv * out_lin[((size_t)t * NUNITS + n) * 128 + e];
  tok_feat[n * 128 + e] = a;
}

// ---------------------------------------------------------------------------
extern "C" void kernel_launch(void* const* d_in, const int* in_sizes, int n_in,
                              void* d_out, int out_size, void* d_ws, size_t ws_size,
                              hipStream_t stream)
{
  const int*   units = (const int*)d_in[0];
  const int*   paths = (const int*)d_in[1];
  const int*   upd   = (const int*)d_in[2];
  const int*   ppd   = (const int*)d_in[3];
  const float* emb   = (const float*)d_in[4];
  const float* tWif  = (const float*)d_in[5];
  const float* tWhf  = (const float*)d_in[6];
  const float* tbf   = (const float*)d_in[7];
  const float* tWib  = (const float*)d_in[8];
  const float* tWhb  = (const float*)d_in[9];
  const float* tbb   = (const float*)d_in[10];
  const float* linW  = (const float*)d_in[11];
  const float* linb  = (const float*)d_in[12];
  const float* lng   = (const float*)d_in[13];
  const float* lnb   = (const float*)d_in[14];
  const float* attw  = (const float*)d_in[15];
  const float* attb  = (const float*)d_in[16];
  const float* pWif  = (const float*)d_in[17];
  const float* pWhf  = (const float*)d_in[18];
  const float* pbf   = (const float*)d_in[19];
  const float* pWib  = (const float*)d_in[20];
  const float* pWhb  = (const float*)d_in[21];
  const float* pbb   = (const float*)d_in[22];
  const float* ulW   = (const float*)d_in[23];
  const float* ulb   = (const float*)d_in[24];

  float* ws = (float*)d_ws;
  int*   ip = (int*)(ws + OFF_INT);
  if (ws_size < WS_FLOATS * sizeof(float)) return;

  unsigned short* wfrag   = (unsigned short*)(ws + OFF_WFRAG);
  unsigned short* linfrag = (unsigned short*)(ws + OFF_LINFRAG);
  unsigned short* ulfrag  = linfrag + 32768;
  unsigned short* OUTF  = (unsigned short*)(ws + OFF_OUTF);
  unsigned short* OUTB  = (unsigned short*)(ws + OFF_OUTB);
  unsigned short* POUTF = (unsigned short*)(ws + OFF_POUTF);
  unsigned short* POUTB = (unsigned short*)(ws + OFF_POUTB);

  prep_kernel<<<2304, 256, 0, stream>>>(tWif, tWhf, tWib, tWhb,
                                        pWif, pWhf, pWib, pWhb,
                                        linW, ulW, ws);
  len_kernel<<<20, 256, 0, stream>>>(units, paths, upd, ppd, ip);

  lstm_kernel<0><<<dim3(128, 2), 1024, 0, stream>>>(
      wfrag, tbf, tbb, emb, units, ip /*tok_len*/, nullptr, nullptr, nullptr,
      OUTF, OUTB);

  gemm_mfma<1><<<1024, 256, 0, stream>>>(
      OUTF, OUTB, ip /*tok_len*/, linfrag, linb,
      ws + OFF_OUTLIN, ws + OFF_SCORES, lng, lnb, attw, attb, units, NUNITS);

  softmax_feat_kernel<<<4096, 128, 0, stream>>>(ws + OFF_SCORES, ws + OFF_OUTLIN,
                                                ws + OFF_TOKFEAT);

  lstm_kernel<1><<<dim3(128, 2), 1024, 0, stream>>>(
      wfrag, pbf, pbb, ws + OFF_TOKFEAT, paths, ip + 5120 /*p_len*/,
      ip + 4096 /*fe*/, ip + 6144 /*off_p*/, ip + 7168 /*un_p*/,
      POUTF, POUTB);

  gemm_mfma<0><<<512, 256, 0, stream>>>(
      POUTF, POUTB, ip + 5120 /*p_len*/, ulfrag, ulb,
      (float*)d_out, nullptr, nullptr, nullptr, nullptr, nullptr, nullptr, NPATHS);
}

// Round 6
// 320.662 us; speedup vs baseline: 9.6215x; 1.0622x over previous
//
#include <hip/hip_runtime.h>
#include <cstdint>
#include <cstddef>

// Problem constants
#define T_TOKN 16
#define NUNITS 4096
#define LPATH  32
#define NPATHS 1024
#define BNUM   8

typedef __attribute__((ext_vector_type(8))) short short8;   // 8 bf16 in 4 VGPRs
typedef __attribute__((ext_vector_type(4))) short short4x;  // 4 bf16 in 2 VGPRs
typedef __attribute__((ext_vector_type(4))) float f32x4;    // MFMA accumulator

// ws float offsets
enum : size_t {
  OFF_WFRAG   = 0,                        // 524288 ushort: lstm W frags [tf|tb|pf|pb]
  OFF_LINFRAG = 262144,                   // 65536 ushort: lin/ul B-frags
  OFF_OUTF    = 294912,                   // token fwd h, bf16 16x4096x128
  OFF_OUTB    = OFF_OUTF + 4194304,       // token bwd h (time-realigned), bf16
  OFF_OUTLIN  = OFF_OUTB + 4194304,       // f32 16x4096x128
  OFF_SCORES  = OFF_OUTLIN + 8388608,     // f32 16x4096
  OFF_TOKFEAT = OFF_SCORES + 65536,       // f32 4096x128
  OFF_POUTF   = OFF_TOKFEAT + 524288,     // path fwd h, bf16 32x1024x128
  OFF_POUTB   = OFF_POUTF + 2097152,
  OFF_INT     = OFF_POUTB + 2097152,      // ints: tok_len 4096 | fe 1024 | p_len 1024 | off_p 1024 | un_p 1024
  WS_FLOATS   = OFF_INT + 8192
};

static __device__ __forceinline__ unsigned short f2bf(float f) {
  union { float f; unsigned u; } v; v.f = f;
  unsigned r = v.u + 0x7fffu + ((v.u >> 16) & 1u);
  return (unsigned short)(r >> 16);
}
static __device__ __forceinline__ unsigned pack_bf(float a, float b) {
  return (unsigned)f2bf(a) | ((unsigned)f2bf(b) << 16);
}
static __device__ __forceinline__ float sigf(float x)      { return 1.f / (1.f + __expf(-x)); }
static __device__ __forceinline__ float tanhfast(float x)  { return 2.f / (1.f + __expf(-2.f * x)) - 1.f; }

// ---------------------------------------------------------------------------
// prep: (a) lstm W frags; (b) lin/ul B-frags; (c) lengths/path metadata
// (merged from the old len_kernel — one fewer dispatch).
// ---------------------------------------------------------------------------
__global__ void prep_kernel(
    const float* __restrict__ tWif, const float* __restrict__ tWhf,
    const float* __restrict__ tWib, const float* __restrict__ tWhb,
    const float* __restrict__ pWif, const float* __restrict__ pWhf,
    const float* __restrict__ pWib, const float* __restrict__ pWhb,
    const float* __restrict__ linW, const float* __restrict__ ulW,
    const int* __restrict__ units, const int* __restrict__ paths,
    const int* __restrict__ upd, const int* __restrict__ ppd,
    float* __restrict__ ws, int* __restrict__ ip)
{
  int idx = blockIdx.x * 256 + threadIdx.x;
  if (idx < 524288) {
    unsigned short* wf = (unsigned short*)(ws + OFF_WFRAG);
    int mat = idx >> 17, rem = idx & 131071;
    int i  = rem & 7;
    int lane = (rem >> 3) & 63;
    int ct = (rem >> 9) & 3;
    int ks = (rem >> 11) & 7;
    int wv = (rem >> 14) & 7;
    int g = wv * 64 + ct * 16 + (lane & 15);
    int k = ks * 32 + ((lane >> 4) << 3) + i;
    const float* Wi; const float* Wh;
    switch (mat) {
      case 0: Wi = tWif; Wh = tWhf; break;
      case 1: Wi = tWib; Wh = tWhb; break;
      case 2: Wi = pWif; Wh = pWhf; break;
      default: Wi = pWib; Wh = pWhb; break;
    }
    float v = (k < 128) ? Wi[g * 128 + k] : Wh[g * 128 + (k - 128)];
    wf[idx] = f2bf(v);
  } else if (idx < 524288 + 65536) {
    unsigned short* lf = (unsigned short*)(ws + OFF_LINFRAG);
    int i2 = idx - 524288;
    int mat = i2 >> 15, rem = i2 & 32767;
    int i  = rem & 7;
    int lane = (rem >> 3) & 63;
    int ks = (rem >> 9) & 7;
    int ct = (rem >> 12) & 7;
    int e = ct * 16 + (lane & 15);
    int k = ks * 32 + ((lane >> 4) << 3) + i;
    const float* W = mat ? ulW : linW;
    lf[i2] = f2bf(W[e * 256 + k]);
  } else if (idx < 589824 + 4096) {
    int n = idx - 589824;
    int len = T_TOKN;
    for (int t = 0; t < T_TOKN; ++t)
      if (units[t * NUNITS + n] == 0) { len = t; break; }
    ip[n] = len;                                   // tok_len
  } else if (idx < 589824 + 5120) {
    int p = idx - (589824 + 4096);
    int* fe_a  = ip + 4096;
    int* p_len = ip + 5120;
    int* off_p = ip + 6144;
    int* un_p  = ip + 7168;
    int cum = 0; int d = BNUM - 1;
    for (int dd = 0; dd < BNUM; ++dd) {
      int c2 = cum + ppd[dd];
      if (p < c2) { d = dd; break; }
      cum = c2;
    }
    int off = 0;
    for (int dd = 0; dd < d; ++dd) off += upd[dd];
    int un = upd[d];
    off_p[p] = off; un_p[p] = un;
    int f = LPATH;
    for (int t = 0; t < LPATH; ++t)
      if (paths[t * NPATHS + p] == -1) { f = t; break; }
    fe_a[p] = f;
    int pl = LPATH;
    for (int t = 0; t < LPATH; ++t) {
      int v = paths[t * NPATHS + p];
      if ((t >= f) || (v < 0) || (v > un)) { pl = t; break; }
    }
    p_len[p] = pl;
  }
}

// ---------------------------------------------------------------------------
// MFMA BiLSTM, 16-wave blocks, resident B (32 gate-cols/wave, 64 VGPR/lane).
// Per step: [write x(t) from prefetch regs] barrier; MFMA (K=256) with
// idx(t+1)/x(t+1) global prefetch overlapped; gates->LDS; barrier; pointwise.
// MODE 0: token (emb gather, M=32, pair-wise pointwise: thread = 2u x 2j).
// MODE 1: path (tok_feat gather w/ keep mask, M=8, scalar pointwise).
// ---------------------------------------------------------------------------
template <int MODE>
__global__ __launch_bounds__(1024, 4) void lstm_kernel(
    const unsigned short* __restrict__ wfragAll,
    const float* __restrict__ biasF, const float* __restrict__ biasB,
    const float* __restrict__ src,       // emb or tok_feat (f32)
    const int* __restrict__ idxsrc,      // units or paths
    const int* __restrict__ lens,        // tok_len or p_len
    const int* __restrict__ fe_a, const int* __restrict__ off_p, const int* __restrict__ un_p,
    unsigned short* __restrict__ outF, unsigned short* __restrict__ outB)
{
  constexpr int NN   = MODE ? NPATHS : NUNITS;
  constexpr int TT   = MODE ? LPATH : T_TOKN;
  constexpr int M    = MODE ? 8 : 32;     // real sequences per block
  constexpr int MR   = MODE ? 16 : 32;    // MFMA tile rows
  constexpr int NRT  = MR / 16;
  constexpr int ASTR = 264;               // A-tile row stride (ushorts)
  constexpr int GSTR = 514;               // gates row stride (f32)

  __shared__ unsigned short ash[MR * ASTR];  // [u][0:128)=x  [u][128:256)=h
  __shared__ float gates[MR * GSTR];

  int tid  = threadIdx.x;
  int dir  = blockIdx.y;
  int n0   = blockIdx.x * M;
  int lane = tid & 63, wv = tid >> 6;       // wv in [0,16)

  // ---- resident B fragments: wave wv covers gates [wv*32, wv*32+32) ----
  const unsigned short* wbase =
      wfragAll + (size_t)((MODE ? 2 : 0) + dir) * 131072;
  int wv8 = wv >> 1;
  short8 bfr[8][2];
#pragma unroll
  for (int ks = 0; ks < 8; ++ks)
#pragma unroll
    for (int c2 = 0; c2 < 2; ++c2) {
      int ct = ((wv & 1) << 1) | c2;
      bfr[ks][c2] = *(const short8*)&wbase[((((wv8 * 8 + ks) * 4 + ct) * 64) + lane) * 8];
    }

  // ---- zero LDS (h region; MODE 1: whole tile incl dummy rows) ----
  if (MODE == 0) {
    for (int i = tid; i < MR * 128; i += 1024)
      ash[(i >> 7) * ASTR + 128 + (i & 127)] = 0;
  } else {
    for (int i = tid; i < MR * ASTR; i += 1024) ash[i] = 0;
  }

  // ---- pointwise thread state ----
  const float* bcp = dir ? biasB : biasF;
  // MODE 0: thread = wave's unit pair x j pair.  MODE 1: 1 unit x 1 j.
  int j2 = MODE ? (tid & 127) : ((tid & 63) * 2);
  int ug = MODE ? (tid >> 7)  : (tid >> 6);
  float2 b2[4];
#pragma unroll
  for (int q = 0; q < 4; ++q) {
    if (MODE == 0) b2[q] = *(const float2*)&bcp[q * 128 + j2];
    else           b2[q] = make_float2(bcp[q * 128 + j2], 0.f);
  }
  constexpr int NU = MODE ? 1 : 2;          // units per pointwise thread
  float cst0[NU], cst1[NU];
  int   ulen[NU];
#pragma unroll
  for (int i = 0; i < NU; ++i) {
    cst0[i] = 0.f; cst1[i] = 0.f;
    ulen[i] = lens[n0 + ug * NU + i];
  }

  // ---- gather thread state ----
  int gu, gk0;
  if (MODE == 0) { gu = tid >> 5; gk0 = (tid & 31) * 4; }   // 32 rows x 32 thr
  else           { gu = tid >> 7; gk0 = tid & 127; }        // 8 rows x 128 thr
  int gn = n0 + gu;
  int glen = lens[gn];
  int gfe = 0, goff = 0, gun = 0;
  if (MODE) { gfe = fe_a[gn]; goff = off_p[gn]; gun = un_p[gn]; }

  // ---- preamble: load x(0) ----
  float4 xq; float xs;
  if (MODE == 0) {
    int tau = dir ? min(max(glen - 1, 0), TT - 1) : 0;
    int tok = idxsrc[tau * NN + gn];
    xq = *(const float4*)&src[(size_t)tok * 128 + gk0];
  } else {
    int tau = dir ? min(max(glen - 1, 0), TT - 1) : 0;
    int v = idxsrc[tau * NN + gn];
    bool keep = (tau < gfe) && (v >= 0) && (v < gun);
    xs = 0.f;
    if (keep) xs = src[(size_t)min(v + goff, NUNITS - 1) * 128 + gk0];
  }
  __syncthreads();   // LDS init complete before first x write (race fix, r4)

  for (int t = 0; t < TT; ++t) {
    // ---- write x(t) from prefetch regs into A-tile x region ----
    if (MODE == 0) {
      short4x x4;
      x4[0] = (short)f2bf(xq.x); x4[1] = (short)f2bf(xq.y);
      x4[2] = (short)f2bf(xq.z); x4[3] = (short)f2bf(xq.w);
      *(short4x*)&ash[gu * ASTR + gk0] = x4;
    } else {
      ash[gu * ASTR + gk0] = f2bf(xs);
    }
    __syncthreads();   // A-tile complete: x(t) + h(t-1)

    // ---- MFMA gate GEMM (K=256, resident B) + next-step gather prefetch ----
    {
      int tn = (t + 1 < TT) ? t + 1 : t;
      int taun = dir ? min(max(glen - 1 - tn, 0), TT - 1) : tn;
      int vn = idxsrc[taun * NN + gn];   // issued early; overlaps MFMA below
      f32x4 acc[NRT][2];
#pragma unroll
      for (int rt = 0; rt < NRT; ++rt)
#pragma unroll
        for (int c2 = 0; c2 < 2; ++c2) {
          f32x4 z = {0.f, 0.f, 0.f, 0.f};
          acc[rt][c2] = z;
        }
#pragma unroll
      for (int ks = 0; ks < 8; ++ks) {
        short8 afr[NRT];
#pragma unroll
        for (int rt = 0; rt < NRT; ++rt)
          afr[rt] = *(const short8*)&ash[(rt * 16 + (lane & 15)) * ASTR + ks * 32 + ((lane >> 4) << 3)];
#pragma unroll
        for (int rt = 0; rt < NRT; ++rt)
#pragma unroll
          for (int c2 = 0; c2 < 2; ++c2)
            acc[rt][c2] = __builtin_amdgcn_mfma_f32_16x16x32_bf16(
                afr[rt], bfr[ks][c2], acc[rt][c2], 0, 0, 0);
      }
      // dependent x(t+1) load — latency overlaps gates-write + barrier
      if (MODE == 0) {
        xq = *(const float4*)&src[(size_t)vn * 128 + gk0];
      } else {
        bool keep = (taun < gfe) && (vn >= 0) && (vn < gun);
        xs = 0.f;
        if (keep) xs = src[(size_t)min(vn + goff, NUNITS - 1) * 128 + gk0];
      }
      // ---- preacts -> LDS gates (C-layout: col=lane&15, row=quad*4+reg) ----
#pragma unroll
      for (int rt = 0; rt < NRT; ++rt)
#pragma unroll
        for (int c2 = 0; c2 < 2; ++c2) {
          int g = wv * 32 + c2 * 16 + (lane & 15);
#pragma unroll
          for (int r = 0; r < 4; ++r) {
            int u = rt * 16 + ((lane >> 4) << 2) + r;
            gates[u * GSTR + g] = acc[rt][c2][r];
          }
        }
    }
    __syncthreads();   // gates ready; all A-tile reads done

    // ---- pointwise LSTM update ----
#pragma unroll
    for (int i = 0; i < NU; ++i) {
      int u = ug * NU + i;
      int n = n0 + u;
      if (MODE == 0) {
        float2 g0 = *(const float2*)&gates[u * GSTR + j2];
        float2 g1 = *(const float2*)&gates[u * GSTR + 128 + j2];
        float2 g2 = *(const float2*)&gates[u * GSTR + 256 + j2];
        float2 g3 = *(const float2*)&gates[u * GSTR + 384 + j2];
        float i0 = sigf(g0.x + b2[0].x), i1 = sigf(g0.y + b2[0].y);
        float f0 = sigf(g1.x + b2[1].x), f1 = sigf(g1.y + b2[1].y);
        float c0 = tanhfast(g2.x + b2[2].x), c1 = tanhfast(g2.y + b2[2].y);
        float o0 = sigf(g3.x + b2[3].x), o1 = sigf(g3.y + b2[3].y);
        float cA = f0 * cst0[i] + i0 * c0;
        float cB = f1 * cst1[i] + i1 * c1;
        cst0[i] = cA; cst1[i] = cB;
        float h0 = o0 * tanhfast(cA);
        float h1 = o1 * tanhfast(cB);
        unsigned hp = pack_bf(h0, h1);
        *(unsigned*)&ash[u * ASTR + 128 + j2] = hp;
        if (dir == 0) {
          *(unsigned*)&outF[((size_t)t * NN + n) * 128 + j2] = hp;
        } else {
          int L = ulen[i];
          if (t < L) *(unsigned*)&outB[((size_t)(L - 1 - t) * NN + n) * 128 + j2] = hp;
          else       *(unsigned*)&outB[((size_t)t * NN + n) * 128 + j2] = 0;
        }
      } else {
        float p0 = gates[u * GSTR + j2]       + b2[0].x;
        float p1 = gates[u * GSTR + 128 + j2] + b2[1].x;
        float p2 = gates[u * GSTR + 256 + j2] + b2[2].x;
        float p3 = gates[u * GSTR + 384 + j2] + b2[3].x;
        float ig = sigf(p0), fg = sigf(p1), gg = tanhfast(p2), og = sigf(p3);
        float c = fg * cst0[i] + ig * gg;
        cst0[i] = c;
        float h = og * tanhfast(c);
        unsigned short hb = f2bf(h);
        ash[u * ASTR + 128 + j2] = hb;
        if (dir == 0) {
          outF[((size_t)t * NN + n) * 128 + j2] = hb;
        } else {
          int L = ulen[i];
          if (t < L) outB[((size_t)(L - 1 - t) * NN + n) * 128 + j2] = hb;
          else       outB[((size_t)t * NN + n) * 128 + j2] = 0;
        }
      }
    }
    // next-iter x write touches only x region (disjoint from h/gates) -> safe
  }
}

// ---------------------------------------------------------------------------
// MFMA GEMM: rows x 128, K=256, A = bf16 [INf|INb] from global, B resident
// (64 VGPR/lane, 4 waves cover 128 cols).  C+bias -> LDS tile -> epilogue.
// EPI 0: row-validity mask on A (invalid rows -> OUT = bias), f32 store.
// EPI 1: store OUT + fused LayerNorm+tanh+attention scores.
// ---------------------------------------------------------------------------
template <int EPI>
__global__ __launch_bounds__(256) void gemm_mfma(
    const unsigned short* __restrict__ INf, const unsigned short* __restrict__ INb,
    const int* __restrict__ lens,
    const unsigned short* __restrict__ Bfrag, const float* __restrict__ bias,
    float* __restrict__ OUT, float* __restrict__ scores,
    const float* __restrict__ lng, const float* __restrict__ lnb,
    const float* __restrict__ attw, const float* __restrict__ attb,
    const int* __restrict__ units, int Nn)
{
  constexpr int OSTR = 132;
  __shared__ float outs[64 * OSTR];
  __shared__ float red1[256];
  __shared__ float red2[256];
  __shared__ float rowm[64], rowr[64];
  __shared__ float awsh[128], lgsh[128], lbsh[128];

  int tid = threadIdx.x, lane = tid & 63, wv = tid >> 6;
  int row0 = blockIdx.x * 64;
  int t = row0 / Nn, n0 = row0 % Nn;   // 64-row blocks never straddle t

  if (EPI == 1 && tid < 128) {
    awsh[tid] = attw[tid]; lgsh[tid] = lng[tid]; lbsh[tid] = lnb[tid];
  }

  short8 bfr[8][2];
#pragma unroll
  for (int ks = 0; ks < 8; ++ks)
#pragma unroll
    for (int c2 = 0; c2 < 2; ++c2) {
      int ct = wv * 2 + c2;
      bfr[ks][c2] = *(const short8*)&Bfrag[(((ct * 8 + ks) * 64) + lane) * 8];
    }

  int rb = lane & 15;
  int koq = (lane >> 4) << 3;
  bool val[4];
#pragma unroll
  for (int rt = 0; rt < 4; ++rt)
    val[rt] = (EPI == 1) ? true : (t < lens[n0 + rt * 16 + rb]);

  f32x4 acc[4][2];
#pragma unroll
  for (int rt = 0; rt < 4; ++rt)
#pragma unroll
    for (int c2 = 0; c2 < 2; ++c2) {
      f32x4 z = {0.f, 0.f, 0.f, 0.f};
      acc[rt][c2] = z;
    }

#pragma unroll
  for (int ks = 0; ks < 8; ++ks) {
    const unsigned short* P = (ks < 4) ? INf : INb;
    int koff = (ks & 3) * 32 + koq;
#pragma unroll
    for (int rt = 0; rt < 4; ++rt) {
      short8 a = {0, 0, 0, 0, 0, 0, 0, 0};
      if (val[rt])
        a = *(const short8*)&P[((size_t)(row0 + rt * 16 + rb)) * 128 + koff];
#pragma unroll
      for (int c2 = 0; c2 < 2; ++c2)
        acc[rt][c2] = __builtin_amdgcn_mfma_f32_16x16x32_bf16(
            a, bfr[ks][c2], acc[rt][c2], 0, 0, 0);
    }
  }

  float bc[2];
#pragma unroll
  for (int c2 = 0; c2 < 2; ++c2) bc[c2] = bias[wv * 32 + c2 * 16 + rb];
#pragma unroll
  for (int rt = 0; rt < 4; ++rt)
#pragma unroll
    for (int c2 = 0; c2 < 2; ++c2) {
      int col = wv * 32 + c2 * 16 + rb;
      int ub  = rt * 16 + ((lane >> 4) << 2);
#pragma unroll
      for (int r = 0; r < 4; ++r)
        outs[(ub + r) * OSTR + col] = acc[rt][c2][r] + bc[c2];
    }
  __syncthreads();

  int row = tid >> 2, seg = tid & 3;
  const float* rp = &outs[row * OSTR + seg * 32];
  size_t go = ((size_t)(row0 + row)) * 128 + seg * 32;

  if (EPI == 0) {
#pragma unroll
    for (int x = 0; x < 8; ++x)
      *(f32x4*)&OUT[go + x * 4] = *(const f32x4*)&rp[x * 4];
  } else {
    f32x4 v[8];
    float s = 0.f, s2 = 0.f;
#pragma unroll
    for (int x = 0; x < 8; ++x) {
      v[x] = *(const f32x4*)&rp[x * 4];
#pragma unroll
      for (int c = 0; c < 4; ++c) { s += v[x][c]; s2 += v[x][c] * v[x][c]; }
    }
    red1[tid] = s; red2[tid] = s2;
    __syncthreads();
    if (tid < 64) {
      float a = red1[tid * 4] + red1[tid * 4 + 1] + red1[tid * 4 + 2] + red1[tid * 4 + 3];
      float b = red2[tid * 4] + red2[tid * 4 + 1] + red2[tid * 4 + 2] + red2[tid * 4 + 3];
      float m = a * (1.f / 128.f);
      float var = b * (1.f / 128.f) - m * m;
      rowm[tid] = m;
      rowr[tid] = rsqrtf(var + 1e-5f);
    }
    __syncthreads();
    float m = rowm[row], rs = rowr[row];
    float sp = 0.f;
#pragma unroll
    for (int x = 0; x < 8; ++x) {
#pragma unroll
      for (int c = 0; c < 4; ++c) {
        int col = seg * 32 + x * 4 + c;
        float q = tanhfast((v[x][c] - m) * rs * lgsh[col] + lbsh[col]);
        sp += q * awsh[col];
      }
      *(f32x4*)&OUT[go + x * 4] = v[x];
    }
    red1[tid] = sp;
    __syncthreads();
    if (tid < 64) {
      float s3 = red1[tid * 4] + red1[tid * 4 + 1] + red1[tid * 4 + 2] + red1[tid * 4 + 3]
               + attb[0];
      int n = n0 + tid;
      if (units[t * NUNITS + n] == 0) s3 = -1e9f;
      scores[t * NUNITS + n] = s3;
    }
  }
}

// ---------------------------------------------------------------------------
// Softmax over T=16 + attention-weighted pooling -> tok_feat[n][e]
// ---------------------------------------------------------------------------
__global__ __launch_bounds__(128) void softmax_feat_kernel(
    const float* __restrict__ scores, const float* __restrict__ out_lin,
    float* __restrict__ tok_feat)
{
  int n = blockIdx.x;
  int e = threadIdx.x;
  float s[T_TOKN];
  float m = -1e30f;
#pragma unroll
  for (int t = 0; t < T_TOKN; ++t) { s[t] = scores[t * NUNITS + n]; m = fmaxf(m, s[t]); }
  float sum = 0.f;
#pragma unroll
  for (int t = 0; t < T_TOKN; ++t) { s[t] = expf(s[t] - m); sum += s[t]; }
  float inv = 1.f / sum;
  float a = 0.f;
#pragma unroll
  for (int t = 0; t < T_TOKN; ++t)
    a += s[t] * inv * out_lin[((size_t)t * NUNITS + n) * 128 + e];
  tok_feat[n * 128 + e] = a;
}

// ---------------------------------------------------------------------------
extern "C" void kernel_launch(void* const* d_in, const int* in_sizes, int n_in,
                              void* d_out, int out_size, void* d_ws, size_t ws_size,
                              hipStream_t stream)
{
  const int*   units = (const int*)d_in[0];
  const int*   paths = (const int*)d_in[1];
  const int*   upd   = (const int*)d_in[2];
  const int*   ppd   = (const int*)d_in[3];
  const float* emb   = (const float*)d_in[4];
  const float* tWif  = (const float*)d_in[5];
  const float* tWhf  = (const float*)d_in[6];
  const float* tbf   = (const float*)d_in[7];
  const float* tWib  = (const float*)d_in[8];
  const float* tWhb  = (const float*)d_in[9];
  const float* tbb   = (const float*)d_in[10];
  const float* linW  = (const float*)d_in[11];
  const float* linb  = (const float*)d_in[12];
  const float* lng   = (const float*)d_in[13];
  const float* lnb   = (const float*)d_in[14];
  const float* attw  = (const float*)d_in[15];
  const float* attb  = (const float*)d_in[16];
  const float* pWif  = (const float*)d_in[17];
  const float* pWhf  = (const float*)d_in[18];
  const float* pbf   = (const float*)d_in[19];
  const float* pWib  = (const float*)d_in[20];
  const float* pWhb  = (const float*)d_in[21];
  const float* pbb   = (const float*)d_in[22];
  const float* ulW   = (const float*)d_in[23];
  const float* ulb   = (const float*)d_in[24];

  float* ws = (float*)d_ws;
  int*   ip = (int*)(ws + OFF_INT);
  if (ws_size < WS_FLOATS * sizeof(float)) return;

  unsigned short* wfrag   = (unsigned short*)(ws + OFF_WFRAG);
  unsigned short* linfrag = (unsigned short*)(ws + OFF_LINFRAG);
  unsigned short* ulfrag  = linfrag + 32768;
  unsigned short* OUTF  = (unsigned short*)(ws + OFF_OUTF);
  unsigned short* OUTB  = (unsigned short*)(ws + OFF_OUTB);
  unsigned short* POUTF = (unsigned short*)(ws + OFF_POUTF);
  unsigned short* POUTB = (unsigned short*)(ws + OFF_POUTB);

  prep_kernel<<<2324, 256, 0, stream>>>(tWif, tWhf, tWib, tWhb,
                                        pWif, pWhf, pWib, pWhb,
                                        linW, ulW, units, paths, upd, ppd,
                                        ws, ip);

  lstm_kernel<0><<<dim3(128, 2), 1024, 0, stream>>>(
      wfrag, tbf, tbb, emb, units, ip /*tok_len*/, nullptr, nullptr, nullptr,
      OUTF, OUTB);

  gemm_mfma<1><<<1024, 256, 0, stream>>>(
      OUTF, OUTB, ip /*tok_len*/, linfrag, linb,
      ws + OFF_OUTLIN, ws + OFF_SCORES, lng, lnb, attw, attb, units, NUNITS);

  softmax_feat_kernel<<<4096, 128, 0, stream>>>(ws + OFF_SCORES, ws + OFF_OUTLIN,
                                                ws + OFF_TOKFEAT);

  lstm_kernel<1><<<dim3(128, 2), 1024, 0, stream>>>(
      wfrag, pbf, pbb, ws + OFF_TOKFEAT, paths, ip + 5120 /*p_len*/,
      ip + 4096 /*fe*/, ip + 6144 /*off_p*/, ip + 7168 /*un_p*/,
      POUTF, POUTB);

  gemm_mfma<0><<<512, 256, 0, stream>>>(
      POUTF, POUTB, ip + 5120 /*p_len*/, ulfrag, ulb,
      (float*)d_out, nullptr, nullptr, nullptr, nullptr, nullptr, nullptr, NPATHS);
}